// Round 5
// baseline (1982.581 us; speedup 1.0000x reference)
//
#include <hip/hip_runtime.h>

#define N_USERS 100000
#define N_ITEMS 50001
#define N_EDGES 1000000
#define D 64
#define BATCH 4096
#define MAXLEN 50

// buckets: users 128 rows/bucket (shift 7), items 64 rows/bucket (shift 6)
// 99999>>7 = 781, 50000>>6 = 781 -> both 782 buckets
#define NBU 782
#define NBI 782
#define EPB 4096

// ---------- bf16 helpers (manual, RNE encode / exact decode) ----------
__device__ __forceinline__ float bf_lo(unsigned u) { return __uint_as_float(u << 16); }
__device__ __forceinline__ float bf_hi(unsigned u) { return __uint_as_float(u & 0xffff0000u); }
__device__ __forceinline__ unsigned bf_pack2(float a, float b) {
    unsigned ba = __float_as_uint(a);
    unsigned bb = __float_as_uint(b);
    ba += 0x7fffu + ((ba >> 16) & 1u);
    bb += 0x7fffu + ((bb >> 16) & 1u);
    return (ba >> 16) | (bb & 0xffff0000u);
}

// ---------------- fp32 -> bf16 table convert ----------------
__global__ __launch_bounds__(256) void convert_kernel(
    const float* __restrict__ src, unsigned* __restrict__ dst, int npairs)
{
    int i = blockIdx.x * 256 + threadIdx.x;
    if (i < npairs) {
        float2 f = ((const float2*)src)[i];
        dst[i] = bf_pack2(f.x, f.y);
    }
}

// ---------------- bucket histogram (LDS-aggregated) ----------------
__global__ __launch_bounds__(256) void bucket_hist_kernel(
    const int* __restrict__ eu, const int* __restrict__ ei,
    int* __restrict__ bcnt_u, int* __restrict__ bcnt_i)
{
    __shared__ int hu[NBU];
    __shared__ int hi[NBI];
    int tid = threadIdx.x;
    for (int i = tid; i < NBU; i += 256) hu[i] = 0;
    for (int i = tid; i < NBI; i += 256) hi[i] = 0;
    __syncthreads();
    int e0 = blockIdx.x * EPB;
#pragma unroll
    for (int k = 0; k < EPB / 256; ++k) {
        int e = e0 + k * 256 + tid;
        if (e < N_EDGES) {
            atomicAdd(&hu[eu[e] >> 7], 1);
            atomicAdd(&hi[ei[e] >> 6], 1);
        }
    }
    __syncthreads();
    for (int i = tid; i < NBU; i += 256) if (hu[i]) atomicAdd(&bcnt_u[i], hu[i]);
    for (int i = tid; i < NBI; i += 256) if (hi[i]) atomicAdd(&bcnt_i[i], hi[i]);
}

// ---------------- 1-block scan over bucket counts ----------------
__device__ void scan_one(const int* __restrict__ cnt, int* __restrict__ base,
                         int* __restrict__ cur, int n, int tid)
{
    __shared__ int s[1024];
    int c = (tid < n) ? cnt[tid] : 0;
    s[tid] = c;
    __syncthreads();
    for (int off = 1; off < 1024; off <<= 1) {
        int v = (tid >= off) ? s[tid - off] : 0;
        __syncthreads();
        s[tid] += v;
        __syncthreads();
    }
    if (tid < n) {
        int b = s[tid] - c;
        base[tid] = b;
        cur[tid] = b;
        if (tid == n - 1) base[n] = s[tid];
    }
    __syncthreads();
}

__global__ __launch_bounds__(1024) void scan_kernel(
    const int* __restrict__ bcnt_u, const int* __restrict__ bcnt_i,
    int* __restrict__ base_u, int* __restrict__ base_i,
    int* __restrict__ cur_u, int* __restrict__ cur_i)
{
    int tid = threadIdx.x;
    scan_one(bcnt_u, base_u, cur_u, NBU, tid);
    scan_one(bcnt_i, base_i, cur_i, NBI, tid);
}

// ---------------- bin: block-local multi-split into buckets ----------------
// staged entry: .x = (row_local << 20) | src_idx, .y = fp32 val bits
__global__ __launch_bounds__(256) void bin_kernel(
    const int* __restrict__ erow, const int* __restrict__ esrc,
    const float* __restrict__ eval, int* __restrict__ cursor,
    int2* __restrict__ staged, int shift, int nbuckets)
{
    __shared__ int hist[NBU];
    __shared__ int runbase[NBU];
    __shared__ unsigned short rank[EPB];
    int tid = threadIdx.x;
    for (int i = tid; i < nbuckets; i += 256) hist[i] = 0;
    __syncthreads();
    int e0 = blockIdx.x * EPB;
#pragma unroll
    for (int k = 0; k < EPB / 256; ++k) {
        int e = e0 + k * 256 + tid;
        if (e < N_EDGES)
            rank[k * 256 + tid] = (unsigned short)atomicAdd(&hist[erow[e] >> shift], 1);
    }
    __syncthreads();
    for (int i = tid; i < nbuckets; i += 256) {
        int cn = hist[i];
        runbase[i] = cn ? atomicAdd(&cursor[i], cn) : 0;
    }
    __syncthreads();
    int mask = (1 << shift) - 1;
#pragma unroll
    for (int k = 0; k < EPB / 256; ++k) {
        int e = e0 + k * 256 + tid;
        if (e < N_EDGES) {
            int row = erow[e];
            int2 ent;
            ent.x = ((row & mask) << 20) | esrc[e];
            ent.y = __float_as_int(eval[e]);
            staged[runbase[row >> shift] + rank[k * 256 + tid]] = ent;
        }
    }
}

// ---------------- bucket gather with LDS fp32 accumulators ----------------
// one block per bucket; half-wave per edge (lane c handles dims 2c,2c+1)
template<int RB, bool FINAL>
__global__ __launch_bounds__(256) void bucket_gather_kernel(
    const unsigned* __restrict__ src, const int2* __restrict__ staged,
    const int* __restrict__ base, unsigned* __restrict__ dst_bf,
    const float* __restrict__ V0, const unsigned* __restrict__ V1bf,
    float* __restrict__ Vf, int nrows)
{
    __shared__ float acc[RB * 64];
    int tid = threadIdx.x;
    for (int i = tid; i < RB * 64; i += 256) acc[i] = 0.0f;
    __syncthreads();
    int b = blockIdx.x;
    int s = base[b], e = base[b + 1];
    int lane = tid & 63, w = tid >> 6;
    int c = lane & 31, h = lane >> 5;
    int npairs = (e - s + 1) >> 1;
    for (int q = w; q < npairs; q += 8) {
        int qb = q + 4;
        int i1 = s + 2 * q + h;
        int i2 = s + 2 * qb + h;
        int2 e1 = staged[min(i1, e - 1)];
        int2 e2 = staged[min(i2, e - 1)];
        float v1 = (i1 < e) ? __int_as_float(e1.y) : 0.0f;
        float v2 = (qb < npairs && i2 < e) ? __int_as_float(e2.y) : 0.0f;
        int sr1 = e1.x & 0xFFFFF;
        int rl1 = ((unsigned)e1.x) >> 20;
        int sr2 = e2.x & 0xFFFFF;
        int rl2 = ((unsigned)e2.x) >> 20;
        unsigned u1 = src[(size_t)sr1 * 32 + c];
        unsigned u2 = src[(size_t)sr2 * 32 + c];
        atomicAdd(&acc[rl1 * 64 + 2 * c],     v1 * bf_lo(u1));
        atomicAdd(&acc[rl1 * 64 + 2 * c + 1], v1 * bf_hi(u1));
        atomicAdd(&acc[rl2 * 64 + 2 * c],     v2 * bf_lo(u2));
        atomicAdd(&acc[rl2 * 64 + 2 * c + 1], v2 * bf_hi(u2));
    }
    __syncthreads();
    int r0 = b * RB;
    for (int i = tid; i < RB * 32; i += 256) {
        int r = i >> 5, cc = i & 31;
        if (r0 + r < nrows) {
            float a0 = acc[r * 64 + 2 * cc];
            float a1 = acc[r * 64 + 2 * cc + 1];
            if (FINAL) {
                size_t rr = (size_t)(r0 + r);
                float2 v0 = ((const float2*)(V0 + rr * 64))[cc];
                unsigned uu = V1bf[rr * 32 + cc];
                float2 o;
                o.x = (v0.x + bf_lo(uu) + a0) * (1.0f / 3.0f) + v0.x;
                o.y = (v0.y + bf_hi(uu) + a1) * (1.0f / 3.0f) + v0.y;
                ((float2*)(Vf + rr * 64))[cc] = o;
            } else {
                dst_bf[(size_t)(r0 + r) * 32 + cc] = bf_pack2(a0, a1);
            }
        }
    }
}

// ---------------- attention pooling ----------------

__device__ __forceinline__ float wave_sum64(float v) {
#pragma unroll
    for (int o = 1; o < 64; o <<= 1) v += __shfl_xor(v, o, 64);
    return v;
}

__global__ __launch_bounds__(256) void phase2_kernel(
    const float* __restrict__ user_table, const float* __restrict__ Vf,
    const float* __restrict__ Watt, const float* __restrict__ Wb,
    const float* __restrict__ Wagg, const int* __restrict__ uidx,
    const int* __restrict__ ctx, float* __restrict__ out)
{
    __shared__ __align__(16) float seqrow[4][64];
    __shared__ __align__(16) float xbuf[4][64];
    __shared__ __align__(16) float pooled_s[4][64];
    __shared__ int idxbuf[4][MAXLEN];

    const int tid = threadIdx.x;
    const int w = tid >> 6;
    const int lane = tid & 63;
    const int b = blockIdx.x * 4 + w;

    float wa[D], wg[D];
    {
        const float4* wr = (const float4*)(Watt + (size_t)lane * D);
        const float4* gr = (const float4*)(Wagg + (size_t)lane * D);
#pragma unroll
        for (int k = 0; k < 16; ++k) {
            float4 a = wr[k];
            float4 g = gr[k];
            wa[4 * k + 0] = a.x; wa[4 * k + 1] = a.y;
            wa[4 * k + 2] = a.z; wa[4 * k + 3] = a.w;
            wg[4 * k + 0] = g.x; wg[4 * k + 1] = g.y;
            wg[4 * k + 2] = g.z; wg[4 * k + 3] = g.w;
        }
    }
    float bias = Wb[lane];
    int uid = uidx[b];
    float id_e = user_table[(size_t)uid * D + lane];

    for (int l = 0; l < MAXLEN; ++l) {
        int ci = ctx[b * MAXLEN + l];
        if (lane == 0) idxbuf[w][l] = ci;
        float s = Vf[(size_t)ci * D + lane];
        seqrow[w][lane] = s;
        float acc0 = bias, acc1 = 0.f, acc2 = 0.f, acc3 = 0.f;
#pragma unroll
        for (int d = 0; d < D; d += 4) {
            float4 s4 = *(const float4*)&seqrow[w][d];
            acc0 += s4.x * wa[d + 0];
            acc1 += s4.y * wa[d + 1];
            acc2 += s4.z * wa[d + 2];
            acc3 += s4.w * wa[d + 3];
        }
        float key = tanhf(acc0 + acc1 + acc2 + acc3);
        float part = key * id_e;
        float rs = s;
        float att = part;
#pragma unroll
        for (int o = 1; o < 64; o <<= 1) {
            att += __shfl_xor(att, o, 64);
            rs += __shfl_xor(rs, o, 64);
        }
        float X = (rs == 0.0f) ? 0.0f : att;
        if (lane == 0) xbuf[w][l] = X;
    }

    float ex = (lane < MAXLEN) ? expf(xbuf[w][lane]) : 0.0f;
    float denom = wave_sum64(ex) + 1e-12f;
    if (lane < MAXLEN) xbuf[w][lane] = ex / denom;

    float pooled = 0.0f;
    for (int l = 0; l < MAXLEN; ++l) {
        int ci = idxbuf[w][l];
        float a = xbuf[w][l];
        pooled += a * Vf[(size_t)ci * D + lane];
    }
    pooled_s[w][lane] = pooled;

    float o0 = 0.f, o1 = 0.f, o2 = 0.f, o3 = 0.f;
#pragma unroll
    for (int d = 0; d < D; d += 4) {
        float4 p4 = *(const float4*)&pooled_s[w][d];
        o0 += p4.x * wg[d + 0];
        o1 += p4.y * wg[d + 1];
        o2 += p4.z * wg[d + 2];
        o3 += p4.w * wg[d + 3];
    }
    float outv = o0 + o1 + o2 + o3;
    out[(size_t)b * D + lane] = 0.5f * id_e + 0.5f * outv;
}

// ---------------- launch ----------------

extern "C" void kernel_launch(void* const* d_in, const int* in_sizes, int n_in,
                              void* d_out, int out_size, void* d_ws, size_t ws_size,
                              hipStream_t stream)
{
    const float* user_table = (const float*)d_in[0];
    const float* item_table = (const float*)d_in[1];
    const float* ev_uv      = (const float*)d_in[2];
    const float* ev_vu      = (const float*)d_in[3];
    const float* Watt       = (const float*)d_in[4];
    const float* Wb         = (const float*)d_in[5];
    const float* Wagg       = (const float*)d_in[6];
    const int*   edge_u     = (const int*)d_in[7];
    const int*   edge_i     = (const int*)d_in[8];
    const int*   uidx       = (const int*)d_in[9];
    const int*   ctx        = (const int*)d_in[10];
    float* out = (float*)d_out;

    // workspace layout
    char* p = (char*)d_ws;
    unsigned* it_bf    = (unsigned*)p; p += (size_t)N_ITEMS * 32 * 4;   // 6.4 MB
    unsigned* u_msg_bf = (unsigned*)p; p += (size_t)N_USERS * 32 * 4;   // 12.8 MB
    unsigned* V1_bf    = (unsigned*)p; p += (size_t)N_ITEMS * 32 * 4;   // 6.4 MB
    float*    Vf       = (float*)p;    p += (size_t)N_ITEMS * D * 4;    // 12.8 MB
    int2*     staged_u = (int2*)p;     p += (size_t)N_EDGES * 8;        // 8 MB
    int2*     staged_i = (int2*)p;     p += (size_t)N_EDGES * 8;        // 8 MB
    int*      bcnt_u   = (int*)p;      p += NBU * 4;                    // contiguous
    int*      bcnt_i   = (int*)p;      p += NBI * 4;                    //  with bcnt_u
    int*      base_u   = (int*)p;      p += (NBU + 1) * 4;
    int*      base_i   = (int*)p;      p += (NBI + 1) * 4;
    int*      cur_u    = (int*)p;      p += NBU * 4;
    int*      cur_i    = (int*)p;      p += NBI * 4;
    // ~54.4 MB total

    hipMemsetAsync(bcnt_u, 0, (NBU + NBI) * 4, stream);

    convert_kernel<<<(N_ITEMS * 32 + 255) / 256, 256, 0, stream>>>(
        item_table, it_bf, N_ITEMS * 32);

    const int hblocks = (N_EDGES + EPB - 1) / EPB;  // 245
    bucket_hist_kernel<<<hblocks, 256, 0, stream>>>(edge_u, edge_i, bcnt_u, bcnt_i);
    scan_kernel<<<1, 1024, 0, stream>>>(bcnt_u, bcnt_i, base_u, base_i, cur_u, cur_i);
    bin_kernel<<<hblocks, 256, 0, stream>>>(edge_u, edge_i, ev_uv, cur_u,
                                            staged_u, 7, NBU);
    bin_kernel<<<hblocks, 256, 0, stream>>>(edge_i, edge_u, ev_vu, cur_i,
                                            staged_i, 6, NBI);

    // layer 1
    bucket_gather_kernel<128, false><<<NBU, 256, 0, stream>>>(
        it_bf, staged_u, base_u, u_msg_bf, nullptr, nullptr, nullptr, N_USERS);
    bucket_gather_kernel<64, false><<<NBI, 256, 0, stream>>>(
        u_msg_bf, staged_i, base_i, V1_bf, nullptr, nullptr, nullptr, N_ITEMS);
    // layer 2 (+ fused combine -> Vf fp32)
    bucket_gather_kernel<128, false><<<NBU, 256, 0, stream>>>(
        V1_bf, staged_u, base_u, u_msg_bf, nullptr, nullptr, nullptr, N_USERS);
    bucket_gather_kernel<64, true><<<NBI, 256, 0, stream>>>(
        u_msg_bf, staged_i, base_i, nullptr, item_table, V1_bf, Vf, N_ITEMS);

    // attention pooling + output
    phase2_kernel<<<BATCH / 4, 256, 0, stream>>>(user_table, Vf, Watt, Wb, Wagg,
                                                 uidx, ctx, out);
}

// Round 6
// 615.362 us; speedup vs baseline: 3.2218x; 3.2218x over previous
//
#include <hip/hip_runtime.h>

#define N_USERS 100000
#define N_ITEMS 50001
#define N_EDGES 1000000
#define D 64
#define BATCH 4096
#define MAXLEN 50

// ---------- bf16 helpers (manual, RNE encode / exact decode) ----------
__device__ __forceinline__ float bf_lo(unsigned u) { return __uint_as_float(u << 16); }
__device__ __forceinline__ float bf_hi(unsigned u) { return __uint_as_float(u & 0xffff0000u); }
__device__ __forceinline__ unsigned bf_pack2(float a, float b) {
    unsigned ba = __float_as_uint(a);
    unsigned bb = __float_as_uint(b);
    ba += 0x7fffu + ((ba >> 16) & 1u);
    bb += 0x7fffu + ((bb >> 16) & 1u);
    return (ba >> 16) | (bb & 0xffff0000u);
}

// ---------------- CSR build ----------------

__global__ __launch_bounds__(256) void hist_kernel(
    const int* __restrict__ eu, const int* __restrict__ ei,
    int* __restrict__ cnt_u, int* __restrict__ cnt_i)
{
    int e = blockIdx.x * 256 + threadIdx.x;
    if (e < N_EDGES) {
        atomicAdd(&cnt_u[eu[e]], 1);
        atomicAdd(&cnt_i[ei[e]], 1);
    }
}

__global__ __launch_bounds__(256) void offsets_kernel(
    int* __restrict__ cnt /* in: counts, out: cursor */,
    int* __restrict__ off, int n, unsigned int* __restrict__ alloc_ctr)
{
    int i = blockIdx.x * 256 + threadIdx.x;
    int lane = threadIdx.x & 63;
    int c = (i < n) ? cnt[i] : 0;
    int pre = c;
#pragma unroll
    for (int o = 1; o < 64; o <<= 1) {
        int t = __shfl_up(pre, o, 64);
        if (lane >= o) pre += t;
    }
    int wave_total = __shfl(pre, 63, 64);
    unsigned int base = 0;
    if (lane == 63) base = atomicAdd(alloc_ctr, (unsigned int)wave_total);
    base = __shfl((int)base, 63, 64);
    int my_off = (int)base + pre - c;  // exclusive
    if (i < n) {
        off[i] = my_off;
        cnt[i] = my_off;  // becomes cursor for scatter
    }
}

// packed CSR entry (4 B):
//   user-dir (dst=user, src=item):  val_q16 << 16 | item_idx   (item < 65536)
//   item-dir (dst=item, src=user):  val_q15 << 17 | user_idx   (user < 131072)
__global__ __launch_bounds__(256) void scatter_kernel(
    const int* __restrict__ eu, const int* __restrict__ ei,
    const float* __restrict__ ev_uv, const float* __restrict__ ev_vu,
    int* __restrict__ cur_u, int* __restrict__ cur_i,
    unsigned* __restrict__ csr_u, unsigned* __restrict__ csr_i)
{
    int e = blockIdx.x * 256 + threadIdx.x;
    if (e < N_EDGES) {
        int u = eu[e], it = ei[e];
        float vu = ev_uv[e];
        float vi = ev_vu[e];
        unsigned qu = (unsigned)(fminf(fmaxf(vu, 0.0f), 1.0f) * 65535.0f + 0.5f);
        unsigned qi = (unsigned)(fminf(fmaxf(vi, 0.0f), 1.0f) * 32767.0f + 0.5f);
        int pu = atomicAdd(&cur_u[u], 1);
        csr_u[pu] = (qu << 16) | (unsigned)it;
        int pi = atomicAdd(&cur_i[it], 1);
        csr_i[pi] = (qi << 17) | (unsigned)u;
    }
}

// ---------------- fp32 -> bf16 table convert ----------------
__global__ __launch_bounds__(256) void convert_kernel(
    const float* __restrict__ src, unsigned* __restrict__ dst, int npairs)
{
    int i = blockIdx.x * 256 + threadIdx.x;
    if (i < npairs) {
        float2 f = ((const float2*)src)[i];
        dst[i] = bf_pack2(f.x, f.y);
    }
}

// ---------------- gather spmm over bf16 rows ----------------
// one wave per dst row; half-wave per edge: lane = 32*h + c,
// lane accumulates features (2c, 2c+1) for edge-parity h.
// Out-of-range lanes carry word=0 -> idx 0, val 0 -> harmless.
template<int IDXBITS>
__device__ __forceinline__ void gather_row_bf(
    const unsigned* __restrict__ src, const unsigned* __restrict__ csr,
    int o, int e, int lane, int c, int h, float& A0, float& A1)
{
    constexpr unsigned MASK = (1u << IDXBITS) - 1u;
    constexpr float SCALE = 1.0f / (float)((1u << (32 - IDXBITS)) - 1u);
    float acc0 = 0.0f, acc1 = 0.0f;
    for (int base = o; base < e; base += 64) {
        int n = min(64, e - base);
        unsigned word = 0;
        if (lane < n) word = csr[base + lane];
        int np = (n + 1) >> 1;  // pairs of edges
        int p = 0;
        for (; p + 2 <= np; p += 2) {
            int j = 2 * p;
            unsigned w0 = __shfl((int)word, j + 0, 64);
            unsigned w1 = __shfl((int)word, j + 1, 64);
            unsigned w2 = __shfl((int)word, j + 2, 64);
            unsigned w3 = __shfl((int)word, j + 3, 64);
            unsigned wa = h ? w1 : w0;
            unsigned wb = h ? w3 : w2;
            int ra = (int)(wa & MASK);
            int rb = (int)(wb & MASK);
            float va = (float)(wa >> IDXBITS) * SCALE;
            float vb = (float)(wb >> IDXBITS) * SCALE;
            unsigned ua = src[(size_t)ra * 32 + c];
            unsigned ub = src[(size_t)rb * 32 + c];
            acc0 += va * bf_lo(ua);
            acc1 += va * bf_hi(ua);
            acc0 += vb * bf_lo(ub);
            acc1 += vb * bf_hi(ub);
        }
        for (; p < np; ++p) {
            int j = 2 * p;
            unsigned w0 = __shfl((int)word, j + 0, 64);
            unsigned w1 = __shfl((int)word, j + 1, 64);
            unsigned wa = h ? w1 : w0;
            int ra = (int)(wa & MASK);
            float va = (float)(wa >> IDXBITS) * SCALE;
            unsigned ua = src[(size_t)ra * 32 + c];
            acc0 += va * bf_lo(ua);
            acc1 += va * bf_hi(ua);
        }
    }
    A0 = acc0; A1 = acc1;
}

template<int IDXBITS>
__global__ __launch_bounds__(256) void gather_bf_kernel(
    const unsigned* __restrict__ src, const unsigned* __restrict__ csr,
    const int* __restrict__ off, const int* __restrict__ cur,
    unsigned* __restrict__ dst, int nrows)
{
    int w = (blockIdx.x * 256 + threadIdx.x) >> 6;
    int lane = threadIdx.x & 63;
    if (w >= nrows) return;
    int c = lane & 31, h = lane >> 5;
    float a0, a1;
    gather_row_bf<IDXBITS>(src, csr, off[w], cur[w], lane, c, h, a0, a1);
    a0 += __shfl_xor(a0, 32, 64);
    a1 += __shfl_xor(a1, 32, 64);
    if (lane < 32)
        dst[(size_t)w * 32 + lane] = bf_pack2(a0, a1);
}

// final: V2-gather fused with Vf = (V0 + V1 + V2)/3 + V0; Vf fp32
__global__ __launch_bounds__(256) void gather_final_bf_kernel(
    const unsigned* __restrict__ src, const unsigned* __restrict__ csr,
    const int* __restrict__ off, const int* __restrict__ cur,
    const float* __restrict__ V0, const unsigned* __restrict__ V1bf,
    float* __restrict__ Vf)
{
    int w = (blockIdx.x * 256 + threadIdx.x) >> 6;
    int lane = threadIdx.x & 63;
    if (w >= N_ITEMS) return;
    int c = lane & 31, h = lane >> 5;
    float a0, a1;
    gather_row_bf<17>(src, csr, off[w], cur[w], lane, c, h, a0, a1);
    a0 += __shfl_xor(a0, 32, 64);
    a1 += __shfl_xor(a1, 32, 64);
    if (lane < 32) {
        float2 v0 = *(const float2*)(V0 + (size_t)w * D + 2 * lane);
        unsigned u1 = V1bf[(size_t)w * 32 + lane];
        float2 r;
        r.x = (v0.x + bf_lo(u1) + a0) * (1.0f / 3.0f) + v0.x;
        r.y = (v0.y + bf_hi(u1) + a1) * (1.0f / 3.0f) + v0.y;
        *(float2*)(Vf + (size_t)w * D + 2 * lane) = r;
    }
}

// ---------------- attention pooling ----------------

__device__ __forceinline__ float wave_sum64(float v) {
#pragma unroll
    for (int o = 1; o < 64; o <<= 1) v += __shfl_xor(v, o, 64);
    return v;
}

__global__ __launch_bounds__(256) void phase2_kernel(
    const float* __restrict__ user_table, const float* __restrict__ Vf,
    const float* __restrict__ Watt, const float* __restrict__ Wb,
    const float* __restrict__ Wagg, const int* __restrict__ uidx,
    const int* __restrict__ ctx, float* __restrict__ out)
{
    __shared__ __align__(16) float seqrow[4][64];
    __shared__ __align__(16) float xbuf[4][64];
    __shared__ __align__(16) float pooled_s[4][64];
    __shared__ int idxbuf[4][MAXLEN];

    const int tid = threadIdx.x;
    const int w = tid >> 6;
    const int lane = tid & 63;
    const int b = blockIdx.x * 4 + w;

    float wa[D], wg[D];
    {
        const float4* wr = (const float4*)(Watt + (size_t)lane * D);
        const float4* gr = (const float4*)(Wagg + (size_t)lane * D);
#pragma unroll
        for (int k = 0; k < 16; ++k) {
            float4 a = wr[k];
            float4 g = gr[k];
            wa[4 * k + 0] = a.x; wa[4 * k + 1] = a.y;
            wa[4 * k + 2] = a.z; wa[4 * k + 3] = a.w;
            wg[4 * k + 0] = g.x; wg[4 * k + 1] = g.y;
            wg[4 * k + 2] = g.z; wg[4 * k + 3] = g.w;
        }
    }
    float bias = Wb[lane];
    int uid = uidx[b];
    float id_e = user_table[(size_t)uid * D + lane];

    for (int l = 0; l < MAXLEN; ++l) {
        int ci = ctx[b * MAXLEN + l];
        if (lane == 0) idxbuf[w][l] = ci;
        float s = Vf[(size_t)ci * D + lane];
        seqrow[w][lane] = s;
        float acc0 = bias, acc1 = 0.f, acc2 = 0.f, acc3 = 0.f;
#pragma unroll
        for (int d = 0; d < D; d += 4) {
            float4 s4 = *(const float4*)&seqrow[w][d];
            acc0 += s4.x * wa[d + 0];
            acc1 += s4.y * wa[d + 1];
            acc2 += s4.z * wa[d + 2];
            acc3 += s4.w * wa[d + 3];
        }
        float key = tanhf(acc0 + acc1 + acc2 + acc3);
        float part = key * id_e;
        float rs = s;
        float att = part;
#pragma unroll
        for (int o = 1; o < 64; o <<= 1) {
            att += __shfl_xor(att, o, 64);
            rs += __shfl_xor(rs, o, 64);
        }
        float X = (rs == 0.0f) ? 0.0f : att;
        if (lane == 0) xbuf[w][l] = X;
    }

    float ex = (lane < MAXLEN) ? expf(xbuf[w][lane]) : 0.0f;
    float denom = wave_sum64(ex) + 1e-12f;
    if (lane < MAXLEN) xbuf[w][lane] = ex / denom;

    float pooled = 0.0f;
    for (int l = 0; l < MAXLEN; ++l) {
        int ci = idxbuf[w][l];
        float a = xbuf[w][l];
        pooled += a * Vf[(size_t)ci * D + lane];
    }
    pooled_s[w][lane] = pooled;

    float o0 = 0.f, o1 = 0.f, o2 = 0.f, o3 = 0.f;
#pragma unroll
    for (int d = 0; d < D; d += 4) {
        float4 p4 = *(const float4*)&pooled_s[w][d];
        o0 += p4.x * wg[d + 0];
        o1 += p4.y * wg[d + 1];
        o2 += p4.z * wg[d + 2];
        o3 += p4.w * wg[d + 3];
    }
    float outv = o0 + o1 + o2 + o3;
    out[(size_t)b * D + lane] = 0.5f * id_e + 0.5f * outv;
}

// ---------------- launch ----------------

extern "C" void kernel_launch(void* const* d_in, const int* in_sizes, int n_in,
                              void* d_out, int out_size, void* d_ws, size_t ws_size,
                              hipStream_t stream)
{
    const float* user_table = (const float*)d_in[0];
    const float* item_table = (const float*)d_in[1];
    const float* ev_uv      = (const float*)d_in[2];
    const float* ev_vu      = (const float*)d_in[3];
    const float* Watt       = (const float*)d_in[4];
    const float* Wb         = (const float*)d_in[5];
    const float* Wagg       = (const float*)d_in[6];
    const int*   edge_u     = (const int*)d_in[7];
    const int*   edge_i     = (const int*)d_in[8];
    const int*   uidx       = (const int*)d_in[9];
    const int*   ctx        = (const int*)d_in[10];
    float* out = (float*)d_out;

    // workspace layout (bf16 rows = 32 uints = 128 B)
    char* p = (char*)d_ws;
    unsigned* it_bf    = (unsigned*)p; p += (size_t)N_ITEMS * 32 * 4;   // 6.4 MB
    unsigned* u_msg_bf = (unsigned*)p; p += (size_t)N_USERS * 32 * 4;   // 12.8 MB
    unsigned* V1_bf    = (unsigned*)p; p += (size_t)N_ITEMS * 32 * 4;   // 6.4 MB
    float*    Vf       = (float*)p;    p += (size_t)N_ITEMS * D * 4;    // 12.8 MB
    unsigned* csr_u    = (unsigned*)p; p += (size_t)N_EDGES * 4;        // 4 MB
    unsigned* csr_i    = (unsigned*)p; p += (size_t)N_EDGES * 4;        // 4 MB
    int*      cur_u    = (int*)p;      p += (size_t)N_USERS * 4;
    int*      cur_i    = (int*)p;      p += (size_t)N_ITEMS * 4;
    unsigned int* ctrs = (unsigned int*)p; p += 2 * 4;
    int*      off_u    = (int*)p;      p += (size_t)N_USERS * 4;
    int*      off_i    = (int*)p;      p += (size_t)N_ITEMS * 4;
    // ~47.6 MB total

    hipMemsetAsync(cur_u, 0, ((size_t)N_USERS + N_ITEMS + 2) * 4, stream);

    const int eblocks = (N_EDGES + 255) / 256;
    convert_kernel<<<(N_ITEMS * 32 + 255) / 256, 256, 0, stream>>>(
        item_table, it_bf, N_ITEMS * 32);
    hist_kernel<<<eblocks, 256, 0, stream>>>(edge_u, edge_i, cur_u, cur_i);
    offsets_kernel<<<(N_USERS + 255) / 256, 256, 0, stream>>>(cur_u, off_u, N_USERS, &ctrs[0]);
    offsets_kernel<<<(N_ITEMS + 255) / 256, 256, 0, stream>>>(cur_i, off_i, N_ITEMS, &ctrs[1]);
    scatter_kernel<<<eblocks, 256, 0, stream>>>(edge_u, edge_i, ev_uv, ev_vu,
                                                cur_u, cur_i, csr_u, csr_i);

    const int ublocks = (N_USERS + 3) / 4;
    const int iblocks = (N_ITEMS + 3) / 4;

    // layer 1 (user-dir CSR: src idx = item, 16 bits; item-dir: src idx = user, 17 bits)
    gather_bf_kernel<16><<<ublocks, 256, 0, stream>>>(it_bf, csr_u, off_u, cur_u, u_msg_bf, N_USERS);
    gather_bf_kernel<17><<<iblocks, 256, 0, stream>>>(u_msg_bf, csr_i, off_i, cur_i, V1_bf, N_ITEMS);
    // layer 2 (+ fused combine -> Vf fp32)
    gather_bf_kernel<16><<<ublocks, 256, 0, stream>>>(V1_bf, csr_u, off_u, cur_u, u_msg_bf, N_USERS);
    gather_final_bf_kernel<<<iblocks, 256, 0, stream>>>(u_msg_bf, csr_i, off_i, cur_i,
                                                        item_table, V1_bf, Vf);

    // attention pooling + output
    phase2_kernel<<<BATCH / 4, 256, 0, stream>>>(user_table, Vf, Watt, Wb, Wagg,
                                                 uidx, ctx, out);
}

// Round 7
// 421.050 us; speedup vs baseline: 4.7087x; 1.4615x over previous
//
#include <hip/hip_runtime.h>

#define N_USERS 100000
#define N_ITEMS 50001
#define N_EDGES 1000000
#define D 64
#define BATCH 4096
#define MAXLEN 50

// coarse buckets for the two-phase counting sort
#define SHU 8                         // 256 user rows per bucket
#define SHI 7                         // 128 item rows per bucket
#define NBU ((N_USERS + 255) >> 8)    // 391
#define NBI ((N_ITEMS + 127) >> 7)    // 391
#define EPB 4096                      // edges per bin block
#define HBLOCKS ((N_EDGES + EPB - 1) / EPB)  // 245

// ---------- bf16 helpers (manual, RNE encode / exact decode) ----------
__device__ __forceinline__ float bf_lo(unsigned u) { return __uint_as_float(u << 16); }
__device__ __forceinline__ float bf_hi(unsigned u) { return __uint_as_float(u & 0xffff0000u); }
__device__ __forceinline__ unsigned bf_pack2(float a, float b) {
    unsigned ba = __float_as_uint(a);
    unsigned bb = __float_as_uint(b);
    ba += 0x7fffu + ((ba >> 16) & 1u);
    bb += 0x7fffu + ((bb >> 16) & 1u);
    return (ba >> 16) | (bb & 0xffff0000u);
}

// ---------------- fp32 -> bf16 table convert ----------------
__global__ __launch_bounds__(256) void convert_kernel(
    const float* __restrict__ src, unsigned* __restrict__ dst, int npairs)
{
    int i = blockIdx.x * 256 + threadIdx.x;
    if (i < npairs) {
        float2 f = ((const float2*)src)[i];
        dst[i] = bf_pack2(f.x, f.y);
    }
}

// ---------------- coarse bucket histogram (both dirs, LDS-aggregated) ----------------
__global__ __launch_bounds__(256) void coarse_hist_kernel(
    const int* __restrict__ eu, const int* __restrict__ ei,
    int* __restrict__ bcnt_u, int* __restrict__ bcnt_i)
{
    __shared__ int hu[NBU];
    __shared__ int hi[NBI];
    int tid = threadIdx.x;
    for (int i = tid; i < NBU; i += 256) hu[i] = 0;
    for (int i = tid; i < NBI; i += 256) hi[i] = 0;
    __syncthreads();
    int e0 = blockIdx.x * EPB;
#pragma unroll
    for (int k = 0; k < EPB / 256; ++k) {
        int e = e0 + k * 256 + tid;
        if (e < N_EDGES) {
            atomicAdd(&hu[eu[e] >> SHU], 1);
            atomicAdd(&hi[ei[e] >> SHI], 1);
        }
    }
    __syncthreads();
    for (int i = tid; i < NBU; i += 256) if (hu[i]) atomicAdd(&bcnt_u[i], hu[i]);
    for (int i = tid; i < NBI; i += 256) if (hi[i]) atomicAdd(&bcnt_i[i], hi[i]);
}

// ---------------- scan bucket counts -> bases + cursors (grid=2) ----------------
__global__ __launch_bounds__(256) void scan_kernel(
    const int* __restrict__ bcnt_u, const int* __restrict__ bcnt_i,
    int* __restrict__ base_u, int* __restrict__ base_i,
    int* __restrict__ gcur_u, int* __restrict__ gcur_i)
{
    __shared__ int s[512];
    int t = threadIdx.x;
    const int* cnt = (blockIdx.x == 0) ? bcnt_u : bcnt_i;
    int* base = (blockIdx.x == 0) ? base_u : base_i;
    int* gcur = (blockIdx.x == 0) ? gcur_u : gcur_i;
    const int n = (blockIdx.x == 0) ? NBU : NBI;

    int c0 = (t < n) ? cnt[t] : 0;
    int c1 = (t + 256 < n) ? cnt[t + 256] : 0;
    s[t] = c0; s[t + 256] = c1;
    __syncthreads();
    for (int off = 1; off < 512; off <<= 1) {
        int v0 = (t >= off) ? s[t - off] : 0;
        int v1 = (t + 256 >= off) ? s[t + 256 - off] : 0;
        __syncthreads();
        s[t] += v0; s[t + 256] += v1;
        __syncthreads();
    }
    if (t < n) {
        int b = s[t] - c0;
        base[t] = b; gcur[t] = b;
        if (t == n - 1) base[n] = s[t];
    }
    if (t + 256 < n) {
        int b = s[t + 256] - c1;
        base[t + 256] = b; gcur[t + 256] = b;
        if (t + 256 == n - 1) base[n] = s[t + 256];
    }
}

// ---------------- pass A: bin edges into coarse buckets (both dirs) ----------------
// staged entry (8 B): .x = (row_local << 16) | q_val, .y = src_idx
__global__ __launch_bounds__(256) void bin_kernel(
    const int* __restrict__ eu, const int* __restrict__ ei,
    const float* __restrict__ ev_uv, const float* __restrict__ ev_vu,
    int* __restrict__ gcur_u, int* __restrict__ gcur_i,
    int2* __restrict__ staged_u, int2* __restrict__ staged_i)
{
    __shared__ int hu[NBU];
    __shared__ int hi[NBI];
    __shared__ int rbu[NBU];
    __shared__ int rbi[NBI];
    __shared__ unsigned short ranku[EPB];
    __shared__ unsigned short ranki[EPB];
    int tid = threadIdx.x;
    for (int i = tid; i < NBU; i += 256) hu[i] = 0;
    for (int i = tid; i < NBI; i += 256) hi[i] = 0;
    __syncthreads();
    int e0 = blockIdx.x * EPB;
#pragma unroll
    for (int k = 0; k < EPB / 256; ++k) {
        int slot = k * 256 + tid;
        int e = e0 + slot;
        if (e < N_EDGES) {
            ranku[slot] = (unsigned short)atomicAdd(&hu[eu[e] >> SHU], 1);
            ranki[slot] = (unsigned short)atomicAdd(&hi[ei[e] >> SHI], 1);
        }
    }
    __syncthreads();
    for (int i = tid; i < NBU; i += 256) {
        int cn = hu[i];
        rbu[i] = cn ? atomicAdd(&gcur_u[i], cn) : 0;
    }
    for (int i = tid; i < NBI; i += 256) {
        int cn = hi[i];
        rbi[i] = cn ? atomicAdd(&gcur_i[i], cn) : 0;
    }
    __syncthreads();
#pragma unroll
    for (int k = 0; k < EPB / 256; ++k) {
        int slot = k * 256 + tid;
        int e = e0 + slot;
        if (e < N_EDGES) {
            int u = eu[e], it = ei[e];
            unsigned qu = (unsigned)(fminf(fmaxf(ev_uv[e], 0.0f), 1.0f) * 65535.0f + 0.5f);
            unsigned qi = (unsigned)(fminf(fmaxf(ev_vu[e], 0.0f), 1.0f) * 32767.0f + 0.5f);
            int2 su; su.x = (int)((unsigned)(u & 255) << 16 | qu); su.y = it;
            int2 si; si.x = (int)((unsigned)(it & 127) << 16 | qi); si.y = u;
            staged_u[rbu[u >> SHU] + ranku[slot]] = su;
            staged_i[rbi[it >> SHI] + ranki[slot]] = si;
        }
    }
}

// ---------------- pass B: place within bucket (one block per bucket) ----------------
// csr word: (q << IDXBITS) | src_idx ; offend[row] = {begin, end}
__global__ __launch_bounds__(256) void place_kernel(
    const int2* __restrict__ staged_u, const int2* __restrict__ staged_i,
    const int* __restrict__ base_u, const int* __restrict__ base_i,
    unsigned* __restrict__ csr_u, unsigned* __restrict__ csr_i,
    int2* __restrict__ offend_u, int2* __restrict__ offend_i)
{
    __shared__ int cnt[256];
    __shared__ int s[256];
    __shared__ int cur[256];
    int tid = threadIdx.x;
    int dir_i = (blockIdx.x >= NBU) ? 1 : 0;
    int b = blockIdx.x - (dir_i ? NBU : 0);
    const int2* staged = dir_i ? staged_i : staged_u;
    const int* base = dir_i ? base_i : base_u;
    unsigned* csr = dir_i ? csr_i : csr_u;
    int2* offend = dir_i ? offend_i : offend_u;
    const int NR = dir_i ? 128 : 256;
    const int nrows = dir_i ? N_ITEMS : N_USERS;
    const int idxbits = dir_i ? 17 : 16;

    int sb = base[b], eb = base[b + 1];
    if (tid < NR) cnt[tid] = 0;
    __syncthreads();
    for (int idx = sb + tid; idx < eb; idx += 256) {
        int rl = ((unsigned)staged[idx].x) >> 16;
        atomicAdd(&cnt[rl], 1);
    }
    __syncthreads();
    int c = (tid < NR) ? cnt[tid] : 0;
    s[tid] = c;
    __syncthreads();
    for (int off = 1; off < 256; off <<= 1) {
        int v = (tid >= off) ? s[tid - off] : 0;
        __syncthreads();
        s[tid] += v;
        __syncthreads();
    }
    int excl = s[tid] - c;
    int row = b * NR + tid;
    if (tid < NR && row < nrows) {
        int2 oe; oe.x = sb + excl; oe.y = sb + excl + c;
        offend[row] = oe;
    }
    if (tid < NR) cur[tid] = sb + excl;
    __syncthreads();
    for (int idx = sb + tid; idx < eb; idx += 256) {
        int2 en = staged[idx];
        unsigned w0 = (unsigned)en.x;
        int rl = w0 >> 16;
        unsigned q = w0 & 0xFFFFu;
        int pos = atomicAdd(&cur[rl], 1);
        csr[pos] = (q << idxbits) | (unsigned)en.y;
    }
}

// ---------------- gather spmm over bf16 rows ----------------
// one wave per dst row; half-wave per edge: lane = 32*h + c,
// lane accumulates features (2c, 2c+1) for edge-parity h.
template<int IDXBITS>
__device__ __forceinline__ void gather_row_bf(
    const unsigned* __restrict__ src, const unsigned* __restrict__ csr,
    int o, int e, int lane, int c, int h, float& A0, float& A1)
{
    constexpr unsigned MASK = (1u << IDXBITS) - 1u;
    constexpr float SCALE = 1.0f / (float)((1u << (32 - IDXBITS)) - 1u);
    float acc0 = 0.0f, acc1 = 0.0f;
    for (int base = o; base < e; base += 64) {
        int n = min(64, e - base);
        unsigned word = 0;
        if (lane < n) word = csr[base + lane];
        int np = (n + 1) >> 1;
        int p = 0;
        for (; p + 2 <= np; p += 2) {
            int j = 2 * p;
            unsigned w0 = __shfl((int)word, j + 0, 64);
            unsigned w1 = __shfl((int)word, j + 1, 64);
            unsigned w2 = __shfl((int)word, j + 2, 64);
            unsigned w3 = __shfl((int)word, j + 3, 64);
            unsigned wa = h ? w1 : w0;
            unsigned wb = h ? w3 : w2;
            int ra = (int)(wa & MASK);
            int rb = (int)(wb & MASK);
            float va = (float)(wa >> IDXBITS) * SCALE;
            float vb = (float)(wb >> IDXBITS) * SCALE;
            unsigned ua = src[(size_t)ra * 32 + c];
            unsigned ub = src[(size_t)rb * 32 + c];
            acc0 += va * bf_lo(ua);
            acc1 += va * bf_hi(ua);
            acc0 += vb * bf_lo(ub);
            acc1 += vb * bf_hi(ub);
        }
        for (; p < np; ++p) {
            int j = 2 * p;
            unsigned w0 = __shfl((int)word, j + 0, 64);
            unsigned w1 = __shfl((int)word, j + 1, 64);
            unsigned wa = h ? w1 : w0;
            int ra = (int)(wa & MASK);
            float va = (float)(wa >> IDXBITS) * SCALE;
            unsigned ua = src[(size_t)ra * 32 + c];
            acc0 += va * bf_lo(ua);
            acc1 += va * bf_hi(ua);
        }
    }
    A0 = acc0; A1 = acc1;
}

template<int IDXBITS>
__global__ __launch_bounds__(256) void gather_bf_kernel(
    const unsigned* __restrict__ src, const unsigned* __restrict__ csr,
    const int2* __restrict__ offend,
    unsigned* __restrict__ dst, int nrows)
{
    int w = (blockIdx.x * 256 + threadIdx.x) >> 6;
    int lane = threadIdx.x & 63;
    if (w >= nrows) return;
    int2 oe = offend[w];
    int c = lane & 31, h = lane >> 5;
    float a0, a1;
    gather_row_bf<IDXBITS>(src, csr, oe.x, oe.y, lane, c, h, a0, a1);
    a0 += __shfl_xor(a0, 32, 64);
    a1 += __shfl_xor(a1, 32, 64);
    if (lane < 32)
        dst[(size_t)w * 32 + lane] = bf_pack2(a0, a1);
}

// final: V2-gather fused with Vf = (V0 + V1 + V2)/3 + V0; Vf fp32
__global__ __launch_bounds__(256) void gather_final_bf_kernel(
    const unsigned* __restrict__ src, const unsigned* __restrict__ csr,
    const int2* __restrict__ offend,
    const float* __restrict__ V0, const unsigned* __restrict__ V1bf,
    float* __restrict__ Vf)
{
    int w = (blockIdx.x * 256 + threadIdx.x) >> 6;
    int lane = threadIdx.x & 63;
    if (w >= N_ITEMS) return;
    int2 oe = offend[w];
    int c = lane & 31, h = lane >> 5;
    float a0, a1;
    gather_row_bf<17>(src, csr, oe.x, oe.y, lane, c, h, a0, a1);
    a0 += __shfl_xor(a0, 32, 64);
    a1 += __shfl_xor(a1, 32, 64);
    if (lane < 32) {
        float2 v0 = *(const float2*)(V0 + (size_t)w * D + 2 * lane);
        unsigned u1 = V1bf[(size_t)w * 32 + lane];
        float2 r;
        r.x = (v0.x + bf_lo(u1) + a0) * (1.0f / 3.0f) + v0.x;
        r.y = (v0.y + bf_hi(u1) + a1) * (1.0f / 3.0f) + v0.y;
        *(float2*)(Vf + (size_t)w * D + 2 * lane) = r;
    }
}

// ---------------- attention pooling ----------------

__device__ __forceinline__ float wave_sum64(float v) {
#pragma unroll
    for (int o = 1; o < 64; o <<= 1) v += __shfl_xor(v, o, 64);
    return v;
}

__global__ __launch_bounds__(256) void phase2_kernel(
    const float* __restrict__ user_table, const float* __restrict__ Vf,
    const float* __restrict__ Watt, const float* __restrict__ Wb,
    const float* __restrict__ Wagg, const int* __restrict__ uidx,
    const int* __restrict__ ctx, float* __restrict__ out)
{
    __shared__ __align__(16) float seqrow[4][64];
    __shared__ __align__(16) float xbuf[4][64];
    __shared__ __align__(16) float pooled_s[4][64];
    __shared__ int idxbuf[4][MAXLEN];

    const int tid = threadIdx.x;
    const int w = tid >> 6;
    const int lane = tid & 63;
    const int b = blockIdx.x * 4 + w;

    float wa[D], wg[D];
    {
        const float4* wr = (const float4*)(Watt + (size_t)lane * D);
        const float4* gr = (const float4*)(Wagg + (size_t)lane * D);
#pragma unroll
        for (int k = 0; k < 16; ++k) {
            float4 a = wr[k];
            float4 g = gr[k];
            wa[4 * k + 0] = a.x; wa[4 * k + 1] = a.y;
            wa[4 * k + 2] = a.z; wa[4 * k + 3] = a.w;
            wg[4 * k + 0] = g.x; wg[4 * k + 1] = g.y;
            wg[4 * k + 2] = g.z; wg[4 * k + 3] = g.w;
        }
    }
    float bias = Wb[lane];
    int uid = uidx[b];
    float id_e = user_table[(size_t)uid * D + lane];

    for (int l = 0; l < MAXLEN; ++l) {
        int ci = ctx[b * MAXLEN + l];
        if (lane == 0) idxbuf[w][l] = ci;
        float s = Vf[(size_t)ci * D + lane];
        seqrow[w][lane] = s;
        float acc0 = bias, acc1 = 0.f, acc2 = 0.f, acc3 = 0.f;
#pragma unroll
        for (int d = 0; d < D; d += 4) {
            float4 s4 = *(const float4*)&seqrow[w][d];
            acc0 += s4.x * wa[d + 0];
            acc1 += s4.y * wa[d + 1];
            acc2 += s4.z * wa[d + 2];
            acc3 += s4.w * wa[d + 3];
        }
        float key = tanhf(acc0 + acc1 + acc2 + acc3);
        float part = key * id_e;
        float rs = s;
        float att = part;
#pragma unroll
        for (int o = 1; o < 64; o <<= 1) {
            att += __shfl_xor(att, o, 64);
            rs += __shfl_xor(rs, o, 64);
        }
        float X = (rs == 0.0f) ? 0.0f : att;
        if (lane == 0) xbuf[w][l] = X;
    }

    float ex = (lane < MAXLEN) ? expf(xbuf[w][lane]) : 0.0f;
    float denom = wave_sum64(ex) + 1e-12f;
    if (lane < MAXLEN) xbuf[w][lane] = ex / denom;

    float pooled = 0.0f;
    for (int l = 0; l < MAXLEN; ++l) {
        int ci = idxbuf[w][l];
        float a = xbuf[w][l];
        pooled += a * Vf[(size_t)ci * D + lane];
    }
    pooled_s[w][lane] = pooled;

    float o0 = 0.f, o1 = 0.f, o2 = 0.f, o3 = 0.f;
#pragma unroll
    for (int d = 0; d < D; d += 4) {
        float4 p4 = *(const float4*)&pooled_s[w][d];
        o0 += p4.x * wg[d + 0];
        o1 += p4.y * wg[d + 1];
        o2 += p4.z * wg[d + 2];
        o3 += p4.w * wg[d + 3];
    }
    float outv = o0 + o1 + o2 + o3;
    out[(size_t)b * D + lane] = 0.5f * id_e + 0.5f * outv;
}

// ---------------- launch ----------------

extern "C" void kernel_launch(void* const* d_in, const int* in_sizes, int n_in,
                              void* d_out, int out_size, void* d_ws, size_t ws_size,
                              hipStream_t stream)
{
    const float* user_table = (const float*)d_in[0];
    const float* item_table = (const float*)d_in[1];
    const float* ev_uv      = (const float*)d_in[2];
    const float* ev_vu      = (const float*)d_in[3];
    const float* Watt       = (const float*)d_in[4];
    const float* Wb         = (const float*)d_in[5];
    const float* Wagg       = (const float*)d_in[6];
    const int*   edge_u     = (const int*)d_in[7];
    const int*   edge_i     = (const int*)d_in[8];
    const int*   uidx       = (const int*)d_in[9];
    const int*   ctx        = (const int*)d_in[10];
    float* out = (float*)d_out;

    // workspace layout
    char* p = (char*)d_ws;
    unsigned* it_bf    = (unsigned*)p; p += (size_t)N_ITEMS * 32 * 4;   // 6.4 MB
    unsigned* u_msg_bf = (unsigned*)p; p += (size_t)N_USERS * 32 * 4;   // 12.8 MB
    unsigned* V1_bf    = (unsigned*)p; p += (size_t)N_ITEMS * 32 * 4;   // 6.4 MB
    // staged region (16 MB) — Vf (12.8 MB fp32) aliases it; staged is dead
    // before gather_final writes Vf.
    char*     Sreg     = p;            p += (size_t)N_EDGES * 8 * 2;    // 16 MB
    int2*     staged_u = (int2*)Sreg;
    int2*     staged_i = (int2*)(Sreg + (size_t)N_EDGES * 8);
    float*    Vf       = (float*)Sreg;
    unsigned* csr_u    = (unsigned*)p; p += (size_t)N_EDGES * 4;        // 4 MB
    unsigned* csr_i    = (unsigned*)p; p += (size_t)N_EDGES * 4;        // 4 MB
    int2*     offend_u = (int2*)p;     p += (size_t)N_USERS * 8;        // 0.8 MB
    int2*     offend_i = (int2*)p;     p += (size_t)N_ITEMS * 8;        // 0.4 MB
    int*      bcnt_u   = (int*)p;      p += NBU * 4;                    // contiguous pair
    int*      bcnt_i   = (int*)p;      p += NBI * 4;
    int*      base_u   = (int*)p;      p += (NBU + 1) * 4;
    int*      base_i   = (int*)p;      p += (NBI + 1) * 4;
    int*      gcur_u   = (int*)p;      p += NBU * 4;
    int*      gcur_i   = (int*)p;      p += NBI * 4;
    // ~50.8 MB total

    hipMemsetAsync(bcnt_u, 0, (NBU + NBI) * 4, stream);

    convert_kernel<<<(N_ITEMS * 32 + 255) / 256, 256, 0, stream>>>(
        item_table, it_bf, N_ITEMS * 32);

    coarse_hist_kernel<<<HBLOCKS, 256, 0, stream>>>(edge_u, edge_i, bcnt_u, bcnt_i);
    scan_kernel<<<2, 256, 0, stream>>>(bcnt_u, bcnt_i, base_u, base_i, gcur_u, gcur_i);
    bin_kernel<<<HBLOCKS, 256, 0, stream>>>(edge_u, edge_i, ev_uv, ev_vu,
                                            gcur_u, gcur_i, staged_u, staged_i);
    place_kernel<<<NBU + NBI, 256, 0, stream>>>(staged_u, staged_i, base_u, base_i,
                                                csr_u, csr_i, offend_u, offend_i);

    const int ublocks = (N_USERS + 3) / 4;
    const int iblocks = (N_ITEMS + 3) / 4;

    // layer 1
    gather_bf_kernel<16><<<ublocks, 256, 0, stream>>>(it_bf, csr_u, offend_u, u_msg_bf, N_USERS);
    gather_bf_kernel<17><<<iblocks, 256, 0, stream>>>(u_msg_bf, csr_i, offend_i, V1_bf, N_ITEMS);
    // layer 2 (+ fused combine -> Vf fp32; Vf aliases dead staged region)
    gather_bf_kernel<16><<<ublocks, 256, 0, stream>>>(V1_bf, csr_u, offend_u, u_msg_bf, N_USERS);
    gather_final_bf_kernel<<<iblocks, 256, 0, stream>>>(u_msg_bf, csr_i, offend_i,
                                                        item_table, V1_bf, Vf);

    // attention pooling + output
    phase2_kernel<<<BATCH / 4, 256, 0, stream>>>(user_table, Vf, Watt, Wb, Wagg,
                                                 uidx, ctx, out);
}

// Round 8
// 317.992 us; speedup vs baseline: 6.2347x; 1.3241x over previous
//
#include <hip/hip_runtime.h>

#define N_USERS 100000
#define N_ITEMS 50001
#define N_EDGES 1000000
#define D 64
#define BATCH 4096
#define MAXLEN 50

// coarse buckets for the two-phase counting sort
#define SHU 8
#define SHI 7
#define NBU ((N_USERS + 255) >> 8)    // 391
#define NBI ((N_ITEMS + 127) >> 7)    // 391
#define EPB 4096
#define HBLOCKS ((N_EDGES + EPB - 1) / EPB)  // 245

typedef __attribute__((ext_vector_type(8))) short short8;
typedef __attribute__((ext_vector_type(4))) float f32x4;

// ---------- bf16 helpers ----------
__device__ __forceinline__ float bf_lo(unsigned u) { return __uint_as_float(u << 16); }
__device__ __forceinline__ float bf_hi(unsigned u) { return __uint_as_float(u & 0xffff0000u); }
__device__ __forceinline__ float bf_s(unsigned short s) { return __uint_as_float(((unsigned)s) << 16); }
__device__ __forceinline__ unsigned bf_pack2(float a, float b) {
    unsigned ba = __float_as_uint(a);
    unsigned bb = __float_as_uint(b);
    ba += 0x7fffu + ((ba >> 16) & 1u);
    bb += 0x7fffu + ((bb >> 16) & 1u);
    return (ba >> 16) | (bb & 0xffff0000u);
}
__device__ __forceinline__ float fast_tanh(float x) {
    float e = __expf(2.0f * x);
    return 1.0f - 2.0f * __builtin_amdgcn_rcpf(e + 1.0f);
}

// ---------------- fp32 -> bf16 table convert ----------------
__global__ __launch_bounds__(256) void convert_kernel(
    const float* __restrict__ src, unsigned* __restrict__ dst, int npairs)
{
    int i = blockIdx.x * 256 + threadIdx.x;
    if (i < npairs) {
        float2 f = ((const float2*)src)[i];
        dst[i] = bf_pack2(f.x, f.y);
    }
}

// ---------------- coarse bucket histogram ----------------
__global__ __launch_bounds__(256) void coarse_hist_kernel(
    const int* __restrict__ eu, const int* __restrict__ ei,
    int* __restrict__ bcnt_u, int* __restrict__ bcnt_i)
{
    __shared__ int hu[NBU];
    __shared__ int hi[NBI];
    int tid = threadIdx.x;
    for (int i = tid; i < NBU; i += 256) hu[i] = 0;
    for (int i = tid; i < NBI; i += 256) hi[i] = 0;
    __syncthreads();
    int e0 = blockIdx.x * EPB;
#pragma unroll
    for (int k = 0; k < EPB / 256; ++k) {
        int e = e0 + k * 256 + tid;
        if (e < N_EDGES) {
            atomicAdd(&hu[eu[e] >> SHU], 1);
            atomicAdd(&hi[ei[e] >> SHI], 1);
        }
    }
    __syncthreads();
    for (int i = tid; i < NBU; i += 256) if (hu[i]) atomicAdd(&bcnt_u[i], hu[i]);
    for (int i = tid; i < NBI; i += 256) if (hi[i]) atomicAdd(&bcnt_i[i], hi[i]);
}

// ---------------- scan bucket counts -> bases + cursors ----------------
__global__ __launch_bounds__(256) void scan_kernel(
    const int* __restrict__ bcnt_u, const int* __restrict__ bcnt_i,
    int* __restrict__ base_u, int* __restrict__ base_i,
    int* __restrict__ gcur_u, int* __restrict__ gcur_i)
{
    __shared__ int s[512];
    int t = threadIdx.x;
    const int* cnt = (blockIdx.x == 0) ? bcnt_u : bcnt_i;
    int* base = (blockIdx.x == 0) ? base_u : base_i;
    int* gcur = (blockIdx.x == 0) ? gcur_u : gcur_i;
    const int n = (blockIdx.x == 0) ? NBU : NBI;

    int c0 = (t < n) ? cnt[t] : 0;
    int c1 = (t + 256 < n) ? cnt[t + 256] : 0;
    s[t] = c0; s[t + 256] = c1;
    __syncthreads();
    for (int off = 1; off < 512; off <<= 1) {
        int v0 = (t >= off) ? s[t - off] : 0;
        int v1 = (t + 256 >= off) ? s[t + 256 - off] : 0;
        __syncthreads();
        s[t] += v0; s[t + 256] += v1;
        __syncthreads();
    }
    if (t < n) {
        int b = s[t] - c0;
        base[t] = b; gcur[t] = b;
        if (t == n - 1) base[n] = s[t];
    }
    if (t + 256 < n) {
        int b = s[t + 256] - c1;
        base[t + 256] = b; gcur[t + 256] = b;
        if (t + 256 == n - 1) base[n] = s[t + 256];
    }
}

// ---------------- pass A: bin edges into coarse buckets ----------------
__global__ __launch_bounds__(256) void bin_kernel(
    const int* __restrict__ eu, const int* __restrict__ ei,
    const float* __restrict__ ev_uv, const float* __restrict__ ev_vu,
    int* __restrict__ gcur_u, int* __restrict__ gcur_i,
    int2* __restrict__ staged_u, int2* __restrict__ staged_i)
{
    __shared__ int hu[NBU];
    __shared__ int hi[NBI];
    __shared__ int rbu[NBU];
    __shared__ int rbi[NBI];
    __shared__ unsigned short ranku[EPB];
    __shared__ unsigned short ranki[EPB];
    int tid = threadIdx.x;
    for (int i = tid; i < NBU; i += 256) hu[i] = 0;
    for (int i = tid; i < NBI; i += 256) hi[i] = 0;
    __syncthreads();
    int e0 = blockIdx.x * EPB;
#pragma unroll
    for (int k = 0; k < EPB / 256; ++k) {
        int slot = k * 256 + tid;
        int e = e0 + slot;
        if (e < N_EDGES) {
            ranku[slot] = (unsigned short)atomicAdd(&hu[eu[e] >> SHU], 1);
            ranki[slot] = (unsigned short)atomicAdd(&hi[ei[e] >> SHI], 1);
        }
    }
    __syncthreads();
    for (int i = tid; i < NBU; i += 256) {
        int cn = hu[i];
        rbu[i] = cn ? atomicAdd(&gcur_u[i], cn) : 0;
    }
    for (int i = tid; i < NBI; i += 256) {
        int cn = hi[i];
        rbi[i] = cn ? atomicAdd(&gcur_i[i], cn) : 0;
    }
    __syncthreads();
#pragma unroll
    for (int k = 0; k < EPB / 256; ++k) {
        int slot = k * 256 + tid;
        int e = e0 + slot;
        if (e < N_EDGES) {
            int u = eu[e], it = ei[e];
            unsigned qu = (unsigned)(fminf(fmaxf(ev_uv[e], 0.0f), 1.0f) * 65535.0f + 0.5f);
            unsigned qi = (unsigned)(fminf(fmaxf(ev_vu[e], 0.0f), 1.0f) * 32767.0f + 0.5f);
            int2 su; su.x = (int)((unsigned)(u & 255) << 16 | qu); su.y = it;
            int2 si; si.x = (int)((unsigned)(it & 127) << 16 | qi); si.y = u;
            staged_u[rbu[u >> SHU] + ranku[slot]] = su;
            staged_i[rbi[it >> SHI] + ranki[slot]] = si;
        }
    }
}

// ---------------- pass B: place within bucket ----------------
__global__ __launch_bounds__(256) void place_kernel(
    const int2* __restrict__ staged_u, const int2* __restrict__ staged_i,
    const int* __restrict__ base_u, const int* __restrict__ base_i,
    unsigned* __restrict__ csr_u, unsigned* __restrict__ csr_i,
    int2* __restrict__ offend_u, int2* __restrict__ offend_i)
{
    __shared__ int cnt[256];
    __shared__ int s[256];
    __shared__ int cur[256];
    int tid = threadIdx.x;
    int dir_i = (blockIdx.x >= NBU) ? 1 : 0;
    int b = blockIdx.x - (dir_i ? NBU : 0);
    const int2* staged = dir_i ? staged_i : staged_u;
    const int* base = dir_i ? base_i : base_u;
    unsigned* csr = dir_i ? csr_i : csr_u;
    int2* offend = dir_i ? offend_i : offend_u;
    const int NR = dir_i ? 128 : 256;
    const int nrows = dir_i ? N_ITEMS : N_USERS;
    const int idxbits = dir_i ? 17 : 16;

    int sb = base[b], eb = base[b + 1];
    if (tid < NR) cnt[tid] = 0;
    __syncthreads();
    for (int idx = sb + tid; idx < eb; idx += 256) {
        int rl = ((unsigned)staged[idx].x) >> 16;
        atomicAdd(&cnt[rl], 1);
    }
    __syncthreads();
    int c = (tid < NR) ? cnt[tid] : 0;
    s[tid] = c;
    __syncthreads();
    for (int off = 1; off < 256; off <<= 1) {
        int v = (tid >= off) ? s[tid - off] : 0;
        __syncthreads();
        s[tid] += v;
        __syncthreads();
    }
    int excl = s[tid] - c;
    int row = b * NR + tid;
    if (tid < NR && row < nrows) {
        int2 oe; oe.x = sb + excl; oe.y = sb + excl + c;
        offend[row] = oe;
    }
    if (tid < NR) cur[tid] = sb + excl;
    __syncthreads();
    for (int idx = sb + tid; idx < eb; idx += 256) {
        int2 en = staged[idx];
        unsigned w0 = (unsigned)en.x;
        int rl = w0 >> 16;
        unsigned q = w0 & 0xFFFFu;
        int pos = atomicAdd(&cur[rl], 1);
        csr[pos] = (q << idxbits) | (unsigned)en.y;
    }
}

// ---------------- gather spmm over bf16 rows ----------------
template<int IDXBITS>
__device__ __forceinline__ void gather_row_bf(
    const unsigned* __restrict__ src, const unsigned* __restrict__ csr,
    int o, int e, int lane, int c, int h, float& A0, float& A1)
{
    constexpr unsigned MASK = (1u << IDXBITS) - 1u;
    constexpr float SCALE = 1.0f / (float)((1u << (32 - IDXBITS)) - 1u);
    float acc0 = 0.0f, acc1 = 0.0f;
    for (int base = o; base < e; base += 64) {
        int n = min(64, e - base);
        unsigned word = 0;
        if (lane < n) word = csr[base + lane];
        int np = (n + 1) >> 1;
        int p = 0;
        for (; p + 2 <= np; p += 2) {
            int j = 2 * p;
            unsigned w0 = __shfl((int)word, j + 0, 64);
            unsigned w1 = __shfl((int)word, j + 1, 64);
            unsigned w2 = __shfl((int)word, j + 2, 64);
            unsigned w3 = __shfl((int)word, j + 3, 64);
            unsigned wa = h ? w1 : w0;
            unsigned wb = h ? w3 : w2;
            int ra = (int)(wa & MASK);
            int rb = (int)(wb & MASK);
            float va = (float)(wa >> IDXBITS) * SCALE;
            float vb = (float)(wb >> IDXBITS) * SCALE;
            unsigned ua = src[(size_t)ra * 32 + c];
            unsigned ub = src[(size_t)rb * 32 + c];
            acc0 += va * bf_lo(ua);
            acc1 += va * bf_hi(ua);
            acc0 += vb * bf_lo(ub);
            acc1 += vb * bf_hi(ub);
        }
        for (; p < np; ++p) {
            int j = 2 * p;
            unsigned w0 = __shfl((int)word, j + 0, 64);
            unsigned w1 = __shfl((int)word, j + 1, 64);
            unsigned wa = h ? w1 : w0;
            int ra = (int)(wa & MASK);
            float va = (float)(wa >> IDXBITS) * SCALE;
            unsigned ua = src[(size_t)ra * 32 + c];
            acc0 += va * bf_lo(ua);
            acc1 += va * bf_hi(ua);
        }
    }
    A0 = acc0; A1 = acc1;
}

template<int IDXBITS>
__global__ __launch_bounds__(256) void gather_bf_kernel(
    const unsigned* __restrict__ src, const unsigned* __restrict__ csr,
    const int2* __restrict__ offend,
    unsigned* __restrict__ dst, int nrows)
{
    int w = (blockIdx.x * 256 + threadIdx.x) >> 6;
    int lane = threadIdx.x & 63;
    if (w >= nrows) return;
    int2 oe = offend[w];
    int c = lane & 31, h = lane >> 5;
    float a0, a1;
    gather_row_bf<IDXBITS>(src, csr, oe.x, oe.y, lane, c, h, a0, a1);
    a0 += __shfl_xor(a0, 32, 64);
    a1 += __shfl_xor(a1, 32, 64);
    if (lane < 32)
        dst[(size_t)w * 32 + lane] = bf_pack2(a0, a1);
}

// final: V2-gather fused with Vf = (V0 + V1 + V2)/3 + V0; Vf packed bf16
__global__ __launch_bounds__(256) void gather_final_bf_kernel(
    const unsigned* __restrict__ src, const unsigned* __restrict__ csr,
    const int2* __restrict__ offend,
    const float* __restrict__ V0, const unsigned* __restrict__ V1bf,
    unsigned* __restrict__ Vf_bf)
{
    int w = (blockIdx.x * 256 + threadIdx.x) >> 6;
    int lane = threadIdx.x & 63;
    if (w >= N_ITEMS) return;
    int2 oe = offend[w];
    int c = lane & 31, h = lane >> 5;
    float a0, a1;
    gather_row_bf<17>(src, csr, oe.x, oe.y, lane, c, h, a0, a1);
    a0 += __shfl_xor(a0, 32, 64);
    a1 += __shfl_xor(a1, 32, 64);
    if (lane < 32) {
        float2 v0 = *(const float2*)(V0 + (size_t)w * D + 2 * lane);
        unsigned u1 = V1bf[(size_t)w * 32 + lane];
        float rx = (v0.x + bf_lo(u1) + a0) * (1.0f / 3.0f) + v0.x;
        float ry = (v0.y + bf_hi(u1) + a1) * (1.0f / 3.0f) + v0.y;
        Vf_bf[(size_t)w * 32 + lane] = bf_pack2(rx, ry);
    }
}

// ---------------- attention pooling via MFMA ----------------
// one wave per batch element; Keys[64e x 64l] = Wa * Seq^T with 16x16x32 bf16 MFMA.
// A-frag: A[m=lane&15][k=(lane>>4)*8+j]; B-frag: B[k=(lane>>4)*8+j][n=lane&15];
// C/D:    D[row=(lane>>4)*4+reg][col=lane&15].  (learn_hip m89/m91/m120 verified)
__global__ __launch_bounds__(256) void phase2_kernel(
    const float* __restrict__ user_table, const unsigned* __restrict__ Vf_bf,
    const float* __restrict__ Watt, const float* __restrict__ Wb,
    const float* __restrict__ Wagg, const int* __restrict__ uidx,
    const int* __restrict__ ctx, float* __restrict__ out)
{
    __shared__ __align__(16) unsigned seq[4][64 * 36];   // 64 rows x 72 bf16 (pad)
    __shared__ unsigned short wgT[64 * 72];              // WgT[d][e] bf16, stride 72
    __shared__ __align__(16) float idrow[4][64];
    __shared__ float attn_l[4][64];
    __shared__ float pooled_l[4][64];

    const int tid = threadIdx.x;
    const int w = tid >> 6;
    const int lane = tid & 63;
    const int q = lane >> 4;
    const int n = lane & 15;
    const int b = blockIdx.x * 4 + w;

    // stage WgT once per block (transposed, bf16)
    for (int i = tid; i < 64 * 64; i += 256) {
        int e = i >> 6, d = i & 63;
        unsigned bb = __float_as_uint(Wagg[i]);
        bb += 0x7fffu + ((bb >> 16) & 1u);
        wgT[d * 72 + e] = (unsigned short)(bb >> 16);
    }
    __syncthreads();

    // per-lane register fragments: Wa, bias, ones
    short8 wa_f[4][2];
#pragma unroll
    for (int et = 0; et < 4; ++et)
#pragma unroll
        for (int ks = 0; ks < 2; ++ks) {
            const float* rp = Watt + (size_t)(16 * et + n) * 64 + 32 * ks + 8 * q;
            float4 f0 = *(const float4*)rp;
            float4 f1 = *(const float4*)(rp + 4);
            union { short8 s; unsigned u[4]; } t;
            t.u[0] = bf_pack2(f0.x, f0.y);
            t.u[1] = bf_pack2(f0.z, f0.w);
            t.u[2] = bf_pack2(f1.x, f1.y);
            t.u[3] = bf_pack2(f1.z, f1.w);
            wa_f[et][ks] = t.s;
        }
    f32x4 biasv[4];
#pragma unroll
    for (int et = 0; et < 4; ++et)
        biasv[et] = *(const f32x4*)(Wb + 16 * et + 4 * q);
    short8 ones8;
#pragma unroll
    for (int j = 0; j < 8; ++j) ones8[j] = (short)0x3F80;

    // id embedding row -> LDS -> per-lane frag
    int uid = uidx[b];
    idrow[w][lane] = user_table[(size_t)uid * 64 + lane];
    f32x4 idv[4];
#pragma unroll
    for (int et = 0; et < 4; ++et)
        idv[et] = *(f32x4*)&idrow[w][16 * et + 4 * q];

    // gather 50 seq rows (bf16) into LDS; rows 50..63 left stale (cols masked later)
    int ci = (lane < MAXLEN) ? ctx[b * MAXLEN + lane] : 0;
#pragma unroll 5
    for (int it = 0; it < 25; ++it) {
        int l = 2 * it + (lane >> 5);
        int cc = lane & 31;
        int rsrc = __shfl(ci, l, 64);
        seq[w][l * 36 + cc] = Vf_bf[(size_t)rsrc * 32 + cc];
    }

    // Keys + rowsum via MFMA, then X[l]
    float xs[4];
#pragma unroll
    for (int lt = 0; lt < 4; ++lt) {
        union { short8 s; uint4 u; } B0, B1;
        B0.u = *(const uint4*)&seq[w][(16 * lt + n) * 36 + 4 * q];
        B1.u = *(const uint4*)&seq[w][(16 * lt + n) * 36 + 16 + 4 * q];

        f32x4 rsum = {0.f, 0.f, 0.f, 0.f};
        rsum = __builtin_amdgcn_mfma_f32_16x16x32_bf16(ones8, B0.s, rsum, 0, 0, 0);
        rsum = __builtin_amdgcn_mfma_f32_16x16x32_bf16(ones8, B1.s, rsum, 0, 0, 0);
        float rsv = rsum[0];

        float xacc = 0.0f;
#pragma unroll
        for (int et = 0; et < 4; ++et) {
            f32x4 a = {0.f, 0.f, 0.f, 0.f};
            a = __builtin_amdgcn_mfma_f32_16x16x32_bf16(wa_f[et][0], B0.s, a, 0, 0, 0);
            a = __builtin_amdgcn_mfma_f32_16x16x32_bf16(wa_f[et][1], B1.s, a, 0, 0, 0);
#pragma unroll
            for (int r = 0; r < 4; ++r) {
                float t = fast_tanh(a[r] + biasv[et][r]);
                xacc = fmaf(t, idv[et][r], xacc);
            }
        }
        xacc += __shfl_xor(xacc, 16, 64);
        xacc += __shfl_xor(xacc, 32, 64);
        xs[lt] = (rsv == 0.0f) ? 0.0f : xacc;
    }

    // softmax over l (no max-subtraction, +1e-12, exactly like reference)
    float ex[4];
    float tot = 0.0f;
#pragma unroll
    for (int lt = 0; lt < 4; ++lt) {
        int l = 16 * lt + n;
        ex[lt] = (l < MAXLEN) ? __expf(xs[lt]) : 0.0f;
        tot += ex[lt];
    }
    tot += __shfl_xor(tot, 1, 64);
    tot += __shfl_xor(tot, 2, 64);
    tot += __shfl_xor(tot, 4, 64);
    tot += __shfl_xor(tot, 8, 64);
    float inv = 1.0f / (tot + 1e-12f);
    if (lane < 16) {
#pragma unroll
        for (int lt = 0; lt < 4; ++lt)
            attn_l[w][16 * lt + lane] = ex[lt] * inv;
    }

    // pooled[d=lane] = sum_l attn[l] * seq[l][d]
    float pooled = 0.0f;
    for (int l = 0; l < MAXLEN; ++l) {
        float a = attn_l[w][l];
        unsigned uu = seq[w][l * 36 + (lane >> 1)];
        float sv = (lane & 1) ? bf_hi(uu) : bf_lo(uu);
        pooled = fmaf(a, sv, pooled);
    }
    pooled_l[w][lane] = pooled;

    // out[e=lane] = 0.5*id[e] + 0.5*(pooled . Wg[e])
    float o = 0.0f;
#pragma unroll 8
    for (int d = 0; d < 64; ++d) {
        float pv = pooled_l[w][d];
        float wv = bf_s(wgT[d * 72 + lane]);
        o = fmaf(pv, wv, o);
    }
    out[(size_t)b * 64 + lane] = 0.5f * idrow[w][lane] + 0.5f * o;
}

// ---------------- launch ----------------

extern "C" void kernel_launch(void* const* d_in, const int* in_sizes, int n_in,
                              void* d_out, int out_size, void* d_ws, size_t ws_size,
                              hipStream_t stream)
{
    const float* user_table = (const float*)d_in[0];
    const float* item_table = (const float*)d_in[1];
    const float* ev_uv      = (const float*)d_in[2];
    const float* ev_vu      = (const float*)d_in[3];
    const float* Watt       = (const float*)d_in[4];
    const float* Wb         = (const float*)d_in[5];
    const float* Wagg       = (const float*)d_in[6];
    const int*   edge_u     = (const int*)d_in[7];
    const int*   edge_i     = (const int*)d_in[8];
    const int*   uidx       = (const int*)d_in[9];
    const int*   ctx        = (const int*)d_in[10];
    float* out = (float*)d_out;

    // workspace layout
    char* p = (char*)d_ws;
    unsigned* it_bf    = (unsigned*)p; p += (size_t)N_ITEMS * 32 * 4;   // 6.4 MB
    unsigned* u_msg_bf = (unsigned*)p; p += (size_t)N_USERS * 32 * 4;   // 12.8 MB
    unsigned* V1_bf    = (unsigned*)p; p += (size_t)N_ITEMS * 32 * 4;   // 6.4 MB
    // staged region (16 MB) — Vf_bf (6.4 MB) aliases it; staged dead by then
    char*     Sreg     = p;            p += (size_t)N_EDGES * 8 * 2;    // 16 MB
    int2*     staged_u = (int2*)Sreg;
    int2*     staged_i = (int2*)(Sreg + (size_t)N_EDGES * 8);
    unsigned* Vf_bf    = (unsigned*)Sreg;
    unsigned* csr_u    = (unsigned*)p; p += (size_t)N_EDGES * 4;        // 4 MB
    unsigned* csr_i    = (unsigned*)p; p += (size_t)N_EDGES * 4;        // 4 MB
    int2*     offend_u = (int2*)p;     p += (size_t)N_USERS * 8;        // 0.8 MB
    int2*     offend_i = (int2*)p;     p += (size_t)N_ITEMS * 8;        // 0.4 MB
    int*      bcnt_u   = (int*)p;      p += NBU * 4;
    int*      bcnt_i   = (int*)p;      p += NBI * 4;
    int*      base_u   = (int*)p;      p += (NBU + 1) * 4;
    int*      base_i   = (int*)p;      p += (NBI + 1) * 4;
    int*      gcur_u   = (int*)p;      p += NBU * 4;
    int*      gcur_i   = (int*)p;      p += NBI * 4;

    hipMemsetAsync(bcnt_u, 0, (NBU + NBI) * 4, stream);

    convert_kernel<<<(N_ITEMS * 32 + 255) / 256, 256, 0, stream>>>(
        item_table, it_bf, N_ITEMS * 32);

    coarse_hist_kernel<<<HBLOCKS, 256, 0, stream>>>(edge_u, edge_i, bcnt_u, bcnt_i);
    scan_kernel<<<2, 256, 0, stream>>>(bcnt_u, bcnt_i, base_u, base_i, gcur_u, gcur_i);
    bin_kernel<<<HBLOCKS, 256, 0, stream>>>(edge_u, edge_i, ev_uv, ev_vu,
                                            gcur_u, gcur_i, staged_u, staged_i);
    place_kernel<<<NBU + NBI, 256, 0, stream>>>(staged_u, staged_i, base_u, base_i,
                                                csr_u, csr_i, offend_u, offend_i);

    const int ublocks = (N_USERS + 3) / 4;
    const int iblocks = (N_ITEMS + 3) / 4;

    // layer 1
    gather_bf_kernel<16><<<ublocks, 256, 0, stream>>>(it_bf, csr_u, offend_u, u_msg_bf, N_USERS);
    gather_bf_kernel<17><<<iblocks, 256, 0, stream>>>(u_msg_bf, csr_i, offend_i, V1_bf, N_ITEMS);
    // layer 2 (+ fused combine -> Vf bf16; aliases dead staged region)
    gather_bf_kernel<16><<<ublocks, 256, 0, stream>>>(V1_bf, csr_u, offend_u, u_msg_bf, N_USERS);
    gather_final_bf_kernel<<<iblocks, 256, 0, stream>>>(u_msg_bf, csr_i, offend_i,
                                                        item_table, V1_bf, Vf_bf);

    // attention pooling + output (MFMA)
    phase2_kernel<<<BATCH / 4, 256, 0, stream>>>(user_table, Vf_bf, Watt, Wb, Wagg,
                                                 uidx, ctx, out);
}

// Round 9
// 311.678 us; speedup vs baseline: 6.3610x; 1.0203x over previous
//
#include <hip/hip_runtime.h>

#define N_USERS 100000
#define N_ITEMS 50001
#define N_EDGES 1000000
#define D 64
#define BATCH 4096
#define MAXLEN 50

// coarse buckets for the two-phase counting sort
#define SHU 8
#define SHI 7
#define NBU ((N_USERS + 255) >> 8)    // 391
#define NBI ((N_ITEMS + 127) >> 7)    // 391
#define EPB 4096
#define HBLOCKS ((N_EDGES + EPB - 1) / EPB)  // 245

typedef __attribute__((ext_vector_type(8))) short short8;
typedef __attribute__((ext_vector_type(4))) float f32x4;

// ---------- bf16 helpers ----------
__device__ __forceinline__ float bf_lo(unsigned u) { return __uint_as_float(u << 16); }
__device__ __forceinline__ float bf_hi(unsigned u) { return __uint_as_float(u & 0xffff0000u); }
__device__ __forceinline__ float bf_s(unsigned short s) { return __uint_as_float(((unsigned)s) << 16); }
__device__ __forceinline__ unsigned bf_pack2(float a, float b) {
    unsigned ba = __float_as_uint(a);
    unsigned bb = __float_as_uint(b);
    ba += 0x7fffu + ((ba >> 16) & 1u);
    bb += 0x7fffu + ((bb >> 16) & 1u);
    return (ba >> 16) | (bb & 0xffff0000u);
}
__device__ __forceinline__ float fast_tanh(float x) {
    float e = __expf(2.0f * x);
    return 1.0f - 2.0f * __builtin_amdgcn_rcpf(e + 1.0f);
}

// ---------------- fp32 -> bf16 table convert ----------------
__global__ __launch_bounds__(256) void convert_kernel(
    const float* __restrict__ src, unsigned* __restrict__ dst, int npairs)
{
    int i = blockIdx.x * 256 + threadIdx.x;
    if (i < npairs) {
        float2 f = ((const float2*)src)[i];
        dst[i] = bf_pack2(f.x, f.y);
    }
}

// ---------------- coarse bucket histogram (split by direction) ----------------
__global__ __launch_bounds__(256) void coarse_hist_kernel(
    const int* __restrict__ eu, const int* __restrict__ ei,
    int* __restrict__ bcnt_u, int* __restrict__ bcnt_i)
{
    __shared__ int h[NBU];
    int tid = threadIdx.x;
    int dir_i = (blockIdx.x >= HBLOCKS) ? 1 : 0;
    int blk = blockIdx.x - (dir_i ? HBLOCKS : 0);
    const int* erow = dir_i ? ei : eu;
    int* bcnt = dir_i ? bcnt_i : bcnt_u;
    const int shift = dir_i ? SHI : SHU;
    const int nb = dir_i ? NBI : NBU;

    for (int i = tid; i < nb; i += 256) h[i] = 0;
    __syncthreads();
    int e0 = blk * EPB;
#pragma unroll
    for (int k = 0; k < EPB / 256; ++k) {
        int e = e0 + k * 256 + tid;
        if (e < N_EDGES) atomicAdd(&h[erow[e] >> shift], 1);
    }
    __syncthreads();
    for (int i = tid; i < nb; i += 256) if (h[i]) atomicAdd(&bcnt[i], h[i]);
}

// ---------------- scan bucket counts -> bases + cursors ----------------
__global__ __launch_bounds__(256) void scan_kernel(
    const int* __restrict__ bcnt_u, const int* __restrict__ bcnt_i,
    int* __restrict__ base_u, int* __restrict__ base_i,
    int* __restrict__ gcur_u, int* __restrict__ gcur_i)
{
    __shared__ int s[512];
    int t = threadIdx.x;
    const int* cnt = (blockIdx.x == 0) ? bcnt_u : bcnt_i;
    int* base = (blockIdx.x == 0) ? base_u : base_i;
    int* gcur = (blockIdx.x == 0) ? gcur_u : gcur_i;
    const int n = (blockIdx.x == 0) ? NBU : NBI;

    int c0 = (t < n) ? cnt[t] : 0;
    int c1 = (t + 256 < n) ? cnt[t + 256] : 0;
    s[t] = c0; s[t + 256] = c1;
    __syncthreads();
    for (int off = 1; off < 512; off <<= 1) {
        int v0 = (t >= off) ? s[t - off] : 0;
        int v1 = (t + 256 >= off) ? s[t + 256 - off] : 0;
        __syncthreads();
        s[t] += v0; s[t + 256] += v1;
        __syncthreads();
    }
    if (t < n) {
        int b = s[t] - c0;
        base[t] = b; gcur[t] = b;
        if (t == n - 1) base[n] = s[t];
    }
    if (t + 256 < n) {
        int b = s[t + 256] - c1;
        base[t + 256] = b; gcur[t + 256] = b;
        if (t + 256 == n - 1) base[n] = s[t + 256];
    }
}

// ---------------- pass A: bin edges into coarse buckets (split by dir) ----------------
// staged entry (8 B): .x = (row_local << 16) | q_val, .y = src_idx
__global__ __launch_bounds__(256) void bin_kernel(
    const int* __restrict__ eu, const int* __restrict__ ei,
    const float* __restrict__ ev_uv, const float* __restrict__ ev_vu,
    int* __restrict__ gcur_u, int* __restrict__ gcur_i,
    int2* __restrict__ staged_u, int2* __restrict__ staged_i)
{
    __shared__ int hist[NBU];
    __shared__ int runbase[NBU];
    __shared__ unsigned short rank[EPB];
    int tid = threadIdx.x;
    int dir_i = (blockIdx.x >= HBLOCKS) ? 1 : 0;
    int blk = blockIdx.x - (dir_i ? HBLOCKS : 0);
    const int* erow = dir_i ? ei : eu;
    const int* esrc = dir_i ? eu : ei;
    const float* eval = dir_i ? ev_vu : ev_uv;
    int* gcur = dir_i ? gcur_i : gcur_u;
    int2* staged = dir_i ? staged_i : staged_u;
    const int shift = dir_i ? SHI : SHU;
    const float qs = dir_i ? 32767.0f : 65535.0f;
    const int rlmask = dir_i ? 127 : 255;
    const int nb = dir_i ? NBI : NBU;

    for (int i = tid; i < nb; i += 256) hist[i] = 0;
    __syncthreads();
    int e0 = blk * EPB;
#pragma unroll
    for (int k = 0; k < EPB / 256; ++k) {
        int slot = k * 256 + tid;
        int e = e0 + slot;
        if (e < N_EDGES)
            rank[slot] = (unsigned short)atomicAdd(&hist[erow[e] >> shift], 1);
    }
    __syncthreads();
    for (int i = tid; i < nb; i += 256) {
        int cn = hist[i];
        runbase[i] = cn ? atomicAdd(&gcur[i], cn) : 0;
    }
    __syncthreads();
#pragma unroll
    for (int k = 0; k < EPB / 256; ++k) {
        int slot = k * 256 + tid;
        int e = e0 + slot;
        if (e < N_EDGES) {
            int row = erow[e];
            unsigned q = (unsigned)(fminf(fmaxf(eval[e], 0.0f), 1.0f) * qs + 0.5f);
            int2 en;
            en.x = (int)((unsigned)(row & rlmask) << 16 | q);
            en.y = esrc[e];
            staged[runbase[row >> shift] + rank[slot]] = en;
        }
    }
}

// ---------------- pass B: place within bucket ----------------
__global__ __launch_bounds__(256) void place_kernel(
    const int2* __restrict__ staged_u, const int2* __restrict__ staged_i,
    const int* __restrict__ base_u, const int* __restrict__ base_i,
    unsigned* __restrict__ csr_u, unsigned* __restrict__ csr_i,
    int2* __restrict__ offend_u, int2* __restrict__ offend_i)
{
    __shared__ int cnt[256];
    __shared__ int s[256];
    __shared__ int cur[256];
    int tid = threadIdx.x;
    int dir_i = (blockIdx.x >= NBU) ? 1 : 0;
    int b = blockIdx.x - (dir_i ? NBU : 0);
    const int2* staged = dir_i ? staged_i : staged_u;
    const int* base = dir_i ? base_i : base_u;
    unsigned* csr = dir_i ? csr_i : csr_u;
    int2* offend = dir_i ? offend_i : offend_u;
    const int NR = dir_i ? 128 : 256;
    const int nrows = dir_i ? N_ITEMS : N_USERS;
    const int idxbits = dir_i ? 17 : 16;

    int sb = base[b], eb = base[b + 1];
    if (tid < NR) cnt[tid] = 0;
    __syncthreads();
    for (int idx = sb + tid; idx < eb; idx += 256) {
        int rl = ((unsigned)staged[idx].x) >> 16;
        atomicAdd(&cnt[rl], 1);
    }
    __syncthreads();
    int c = (tid < NR) ? cnt[tid] : 0;
    s[tid] = c;
    __syncthreads();
    for (int off = 1; off < 256; off <<= 1) {
        int v = (tid >= off) ? s[tid - off] : 0;
        __syncthreads();
        s[tid] += v;
        __syncthreads();
    }
    int excl = s[tid] - c;
    int row = b * NR + tid;
    if (tid < NR && row < nrows) {
        int2 oe; oe.x = sb + excl; oe.y = sb + excl + c;
        offend[row] = oe;
    }
    if (tid < NR) cur[tid] = sb + excl;
    __syncthreads();
    for (int idx = sb + tid; idx < eb; idx += 256) {
        int2 en = staged[idx];
        unsigned w0 = (unsigned)en.x;
        int rl = w0 >> 16;
        unsigned q = w0 & 0xFFFFu;
        int pos = atomicAdd(&cur[rl], 1);
        csr[pos] = (q << idxbits) | (unsigned)en.y;
    }
}

// ---------------- gather spmm over bf16 rows (quarter-wave scheme) ----------------
// lane = 16*qq + c8; quarter qq handles edges (4g+qq); lane loads dwordx2
// (dims 4c8..4c8+3). One VMEM instruction covers 4 edges' rows.
template<int IDXBITS>
__device__ __forceinline__ void gather_row_q(
    const unsigned* __restrict__ src, const unsigned* __restrict__ csr,
    int o, int e, int lane, int c8, int qq,
    float& A0, float& A1, float& A2, float& A3)
{
    constexpr unsigned MASK = (1u << IDXBITS) - 1u;
    constexpr float SCALE = 1.0f / (float)((1u << (32 - IDXBITS)) - 1u);
    float a0 = 0.f, a1 = 0.f, a2 = 0.f, a3 = 0.f;
    for (int base = o; base < e; base += 64) {
        int n = min(64, e - base);
        unsigned word = 0;
        if (lane < n) word = csr[base + lane];
        int ng = (n + 3) >> 2;
#pragma unroll 4
        for (int g = 0; g < ng; ++g) {
            unsigned wg_ = (unsigned)__shfl((int)word, 4 * g + qq, 64);
            int r = (int)(wg_ & MASK);
            float v = (float)(wg_ >> IDXBITS) * SCALE;
            uint2 u2 = *(const uint2*)(src + (size_t)r * 32 + 2 * c8);
            a0 = fmaf(v, bf_lo(u2.x), a0);
            a1 = fmaf(v, bf_hi(u2.x), a1);
            a2 = fmaf(v, bf_lo(u2.y), a2);
            a3 = fmaf(v, bf_hi(u2.y), a3);
        }
    }
    A0 = a0; A1 = a1; A2 = a2; A3 = a3;
}

template<int IDXBITS>
__global__ __launch_bounds__(256) void gather_bf_kernel(
    const unsigned* __restrict__ src, const unsigned* __restrict__ csr,
    const int2* __restrict__ offend,
    unsigned* __restrict__ dst, int nrows)
{
    int w = (blockIdx.x * 256 + threadIdx.x) >> 6;
    int lane = threadIdx.x & 63;
    if (w >= nrows) return;
    int2 oe = offend[w];
    int c8 = lane & 15, qq = lane >> 4;
    float a0, a1, a2, a3;
    gather_row_q<IDXBITS>(src, csr, oe.x, oe.y, lane, c8, qq, a0, a1, a2, a3);
    a0 += __shfl_xor(a0, 16, 64); a0 += __shfl_xor(a0, 32, 64);
    a1 += __shfl_xor(a1, 16, 64); a1 += __shfl_xor(a1, 32, 64);
    a2 += __shfl_xor(a2, 16, 64); a2 += __shfl_xor(a2, 32, 64);
    a3 += __shfl_xor(a3, 16, 64); a3 += __shfl_xor(a3, 32, 64);
    if (lane < 16) {
        uint2 o2;
        o2.x = bf_pack2(a0, a1);
        o2.y = bf_pack2(a2, a3);
        *((uint2*)(dst + (size_t)w * 32) + lane) = o2;
    }
}

// final: V2-gather fused with Vf = (V0 + V1 + V2)/3 + V0; Vf packed bf16
__global__ __launch_bounds__(256) void gather_final_bf_kernel(
    const unsigned* __restrict__ src, const unsigned* __restrict__ csr,
    const int2* __restrict__ offend,
    const float* __restrict__ V0, const unsigned* __restrict__ V1bf,
    unsigned* __restrict__ Vf_bf)
{
    int w = (blockIdx.x * 256 + threadIdx.x) >> 6;
    int lane = threadIdx.x & 63;
    if (w >= N_ITEMS) return;
    int2 oe = offend[w];
    int c8 = lane & 15, qq = lane >> 4;
    float a0, a1, a2, a3;
    gather_row_q<17>(src, csr, oe.x, oe.y, lane, c8, qq, a0, a1, a2, a3);
    a0 += __shfl_xor(a0, 16, 64); a0 += __shfl_xor(a0, 32, 64);
    a1 += __shfl_xor(a1, 16, 64); a1 += __shfl_xor(a1, 32, 64);
    a2 += __shfl_xor(a2, 16, 64); a2 += __shfl_xor(a2, 32, 64);
    a3 += __shfl_xor(a3, 16, 64); a3 += __shfl_xor(a3, 32, 64);
    if (lane < 16) {
        float4 v0 = *((const float4*)(V0 + (size_t)w * 64) + lane);
        uint2 u1 = *((const uint2*)(V1bf + (size_t)w * 32) + lane);
        float r0 = (v0.x + bf_lo(u1.x) + a0) * (1.0f / 3.0f) + v0.x;
        float r1 = (v0.y + bf_hi(u1.x) + a1) * (1.0f / 3.0f) + v0.y;
        float r2 = (v0.z + bf_lo(u1.y) + a2) * (1.0f / 3.0f) + v0.z;
        float r3 = (v0.w + bf_hi(u1.y) + a3) * (1.0f / 3.0f) + v0.w;
        uint2 o2;
        o2.x = bf_pack2(r0, r1);
        o2.y = bf_pack2(r2, r3);
        *((uint2*)(Vf_bf + (size_t)w * 32) + lane) = o2;
    }
}

// ---------------- attention pooling via MFMA (round-8, verified) ----------------
__global__ __launch_bounds__(256) void phase2_kernel(
    const float* __restrict__ user_table, const unsigned* __restrict__ Vf_bf,
    const float* __restrict__ Watt, const float* __restrict__ Wb,
    const float* __restrict__ Wagg, const int* __restrict__ uidx,
    const int* __restrict__ ctx, float* __restrict__ out)
{
    __shared__ __align__(16) unsigned seq[4][64 * 36];
    __shared__ unsigned short wgT[64 * 72];
    __shared__ __align__(16) float idrow[4][64];
    __shared__ float attn_l[4][64];
    __shared__ float pooled_l[4][64];

    const int tid = threadIdx.x;
    const int w = tid >> 6;
    const int lane = tid & 63;
    const int q = lane >> 4;
    const int n = lane & 15;
    const int b = blockIdx.x * 4 + w;

    for (int i = tid; i < 64 * 64; i += 256) {
        int e = i >> 6, d = i & 63;
        unsigned bb = __float_as_uint(Wagg[i]);
        bb += 0x7fffu + ((bb >> 16) & 1u);
        wgT[d * 72 + e] = (unsigned short)(bb >> 16);
    }
    __syncthreads();

    short8 wa_f[4][2];
#pragma unroll
    for (int et = 0; et < 4; ++et)
#pragma unroll
        for (int ks = 0; ks < 2; ++ks) {
            const float* rp = Watt + (size_t)(16 * et + n) * 64 + 32 * ks + 8 * q;
            float4 f0 = *(const float4*)rp;
            float4 f1 = *(const float4*)(rp + 4);
            union { short8 s; unsigned u[4]; } t;
            t.u[0] = bf_pack2(f0.x, f0.y);
            t.u[1] = bf_pack2(f0.z, f0.w);
            t.u[2] = bf_pack2(f1.x, f1.y);
            t.u[3] = bf_pack2(f1.z, f1.w);
            wa_f[et][ks] = t.s;
        }
    f32x4 biasv[4];
#pragma unroll
    for (int et = 0; et < 4; ++et)
        biasv[et] = *(const f32x4*)(Wb + 16 * et + 4 * q);
    short8 ones8;
#pragma unroll
    for (int j = 0; j < 8; ++j) ones8[j] = (short)0x3F80;

    int uid = uidx[b];
    idrow[w][lane] = user_table[(size_t)uid * 64 + lane];
    f32x4 idv[4];
#pragma unroll
    for (int et = 0; et < 4; ++et)
        idv[et] = *(f32x4*)&idrow[w][16 * et + 4 * q];

    int ci = (lane < MAXLEN) ? ctx[b * MAXLEN + lane] : 0;
#pragma unroll 5
    for (int it = 0; it < 25; ++it) {
        int l = 2 * it + (lane >> 5);
        int cc = lane & 31;
        int rsrc = __shfl(ci, l, 64);
        seq[w][l * 36 + cc] = Vf_bf[(size_t)rsrc * 32 + cc];
    }

    float xs[4];
#pragma unroll
    for (int lt = 0; lt < 4; ++lt) {
        union { short8 s; uint4 u; } B0, B1;
        B0.u = *(const uint4*)&seq[w][(16 * lt + n) * 36 + 4 * q];
        B1.u = *(const uint4*)&seq[w][(16 * lt + n) * 36 + 16 + 4 * q];

        f32x4 rsum = {0.f, 0.f, 0.f, 0.f};
        rsum = __builtin_amdgcn_mfma_f32_16x16x32_bf16(ones8, B0.s, rsum, 0, 0, 0);
        rsum = __builtin_amdgcn_mfma_f32_16x16x32_bf16(ones8, B1.s, rsum, 0, 0, 0);
        float rsv = rsum[0];

        float xacc = 0.0f;
#pragma unroll
        for (int et = 0; et < 4; ++et) {
            f32x4 a = {0.f, 0.f, 0.f, 0.f};
            a = __builtin_amdgcn_mfma_f32_16x16x32_bf16(wa_f[et][0], B0.s, a, 0, 0, 0);
            a = __builtin_amdgcn_mfma_f32_16x16x32_bf16(wa_f[et][1], B1.s, a, 0, 0, 0);
#pragma unroll
            for (int r = 0; r < 4; ++r) {
                float t = fast_tanh(a[r] + biasv[et][r]);
                xacc = fmaf(t, idv[et][r], xacc);
            }
        }
        xacc += __shfl_xor(xacc, 16, 64);
        xacc += __shfl_xor(xacc, 32, 64);
        xs[lt] = (rsv == 0.0f) ? 0.0f : xacc;
    }

    float ex[4];
    float tot = 0.0f;
#pragma unroll
    for (int lt = 0; lt < 4; ++lt) {
        int l = 16 * lt + n;
        ex[lt] = (l < MAXLEN) ? __expf(xs[lt]) : 0.0f;
        tot += ex[lt];
    }
    tot += __shfl_xor(tot, 1, 64);
    tot += __shfl_xor(tot, 2, 64);
    tot += __shfl_xor(tot, 4, 64);
    tot += __shfl_xor(tot, 8, 64);
    float inv = 1.0f / (tot + 1e-12f);
    if (lane < 16) {
#pragma unroll
        for (int lt = 0; lt < 4; ++lt)
            attn_l[w][16 * lt + lane] = ex[lt] * inv;
    }

    float pooled = 0.0f;
    for (int l = 0; l < MAXLEN; ++l) {
        float a = attn_l[w][l];
        unsigned uu = seq[w][l * 36 + (lane >> 1)];
        float sv = (lane & 1) ? bf_hi(uu) : bf_lo(uu);
        pooled = fmaf(a, sv, pooled);
    }
    pooled_l[w][lane] = pooled;

    float o = 0.0f;
#pragma unroll 8
    for (int d = 0; d < 64; ++d) {
        float pv = pooled_l[w][d];
        float wv = bf_s(wgT[d * 72 + lane]);
        o = fmaf(pv, wv, o);
    }
    out[(size_t)b * 64 + lane] = 0.5f * idrow[w][lane] + 0.5f * o;
}

// ---------------- launch ----------------

extern "C" void kernel_launch(void* const* d_in, const int* in_sizes, int n_in,
                              void* d_out, int out_size, void* d_ws, size_t ws_size,
                              hipStream_t stream)
{
    const float* user_table = (const float*)d_in[0];
    const float* item_table = (const float*)d_in[1];
    const float* ev_uv      = (const float*)d_in[2];
    const float* ev_vu      = (const float*)d_in[3];
    const float* Watt       = (const float*)d_in[4];
    const float* Wb         = (const float*)d_in[5];
    const float* Wagg       = (const float*)d_in[6];
    const int*   edge_u     = (const int*)d_in[7];
    const int*   edge_i     = (const int*)d_in[8];
    const int*   uidx       = (const int*)d_in[9];
    const int*   ctx        = (const int*)d_in[10];
    float* out = (float*)d_out;

    // workspace layout
    char* p = (char*)d_ws;
    unsigned* it_bf    = (unsigned*)p; p += (size_t)N_ITEMS * 32 * 4;   // 6.4 MB
    unsigned* u_msg_bf = (unsigned*)p; p += (size_t)N_USERS * 32 * 4;   // 12.8 MB
    unsigned* V1_bf    = (unsigned*)p; p += (size_t)N_ITEMS * 32 * 4;   // 6.4 MB
    // staged region (16 MB) — Vf_bf (6.4 MB) aliases it; staged dead by then
    char*     Sreg     = p;            p += (size_t)N_EDGES * 8 * 2;    // 16 MB
    int2*     staged_u = (int2*)Sreg;
    int2*     staged_i = (int2*)(Sreg + (size_t)N_EDGES * 8);
    unsigned* Vf_bf    = (unsigned*)Sreg;
    unsigned* csr_u    = (unsigned*)p; p += (size_t)N_EDGES * 4;        // 4 MB
    unsigned* csr_i    = (unsigned*)p; p += (size_t)N_EDGES * 4;        // 4 MB
    int2*     offend_u = (int2*)p;     p += (size_t)N_USERS * 8;        // 0.8 MB
    int2*     offend_i = (int2*)p;     p += (size_t)N_ITEMS * 8;        // 0.4 MB
    int*      bcnt_u   = (int*)p;      p += NBU * 4;
    int*      bcnt_i   = (int*)p;      p += NBI * 4;
    int*      base_u   = (int*)p;      p += (NBU + 1) * 4;
    int*      base_i   = (int*)p;      p += (NBI + 1) * 4;
    int*      gcur_u   = (int*)p;      p += NBU * 4;
    int*      gcur_i   = (int*)p;      p += NBI * 4;

    hipMemsetAsync(bcnt_u, 0, (NBU + NBI) * 4, stream);

    convert_kernel<<<(N_ITEMS * 32 + 255) / 256, 256, 0, stream>>>(
        item_table, it_bf, N_ITEMS * 32);

    coarse_hist_kernel<<<2 * HBLOCKS, 256, 0, stream>>>(edge_u, edge_i, bcnt_u, bcnt_i);
    scan_kernel<<<2, 256, 0, stream>>>(bcnt_u, bcnt_i, base_u, base_i, gcur_u, gcur_i);
    bin_kernel<<<2 * HBLOCKS, 256, 0, stream>>>(edge_u, edge_i, ev_uv, ev_vu,
                                                gcur_u, gcur_i, staged_u, staged_i);
    place_kernel<<<NBU + NBI, 256, 0, stream>>>(staged_u, staged_i, base_u, base_i,
                                                csr_u, csr_i, offend_u, offend_i);

    const int ublocks = (N_USERS + 3) / 4;
    const int iblocks = (N_ITEMS + 3) / 4;

    // layer 1
    gather_bf_kernel<16><<<ublocks, 256, 0, stream>>>(it_bf, csr_u, offend_u, u_msg_bf, N_USERS);
    gather_bf_kernel<17><<<iblocks, 256, 0, stream>>>(u_msg_bf, csr_i, offend_i, V1_bf, N_ITEMS);
    // layer 2 (+ fused combine -> Vf bf16; aliases dead staged region)
    gather_bf_kernel<16><<<ublocks, 256, 0, stream>>>(V1_bf, csr_u, offend_u, u_msg_bf, N_USERS);
    gather_final_bf_kernel<<<iblocks, 256, 0, stream>>>(u_msg_bf, csr_i, offend_i,
                                                        item_table, V1_bf, Vf_bf);

    // attention pooling + output (MFMA)
    phase2_kernel<<<BATCH / 4, 256, 0, stream>>>(user_table, Vf_bf, Watt, Wb, Wagg,
                                                 uidx, ctx, out);
}